// Round 10
// baseline (752.400 us; speedup 1.0000x reference)
//
#include <hip/hip_runtime.h>

typedef unsigned short ushort_t;
typedef unsigned int uint_t;
typedef __attribute__((ext_vector_type(8))) short s8bf;   // 8 x bf16 MFMA fragment
typedef __attribute__((ext_vector_type(4))) float f32x4;  // MFMA accumulator

#define N2 127
#define ACT ((size_t)16*64*127*128)     // activation elements (bf16)
#define HNE ((size_t)16*64*127*64)      // hn elements (bf16)
#define MBW ((size_t)32*3*127*64)       // mailbox words (u32), lives in d_out

__device__ inline float bf_lo(uint_t v){ return __uint_as_float(v << 16); }
__device__ inline float bf_hi(uint_t v){ return __uint_as_float(v & 0xffff0000u); }
__device__ inline ushort_t f2bf(float f){
  uint_t u = __float_as_uint(f);
  uint_t r = ((u >> 16) & 1u) + 0x7fffu;  // RNE
  return (ushort_t)((u + r) >> 16);
}
// packed RNE f32x2 -> bf16x2 (same rounding as f2bf, 1 instr instead of ~10)
__device__ inline uint_t cvt_pk_bf16(float lo, float hi){
  uint_t r;
  asm("v_cvt_pk_bf16_f32 %0, %1, %2" : "=v"(r) : "v"(lo), "v"(hi));
  return r;
}
__device__ inline float bf2f(ushort_t h){ return __uint_as_float(((uint_t)h) << 16); }
__device__ inline float frcp(float x){ return __builtin_amdgcn_rcpf(x); }
__device__ inline float sigm(float x){ return frcp(1.f + __expf(-x)); }
__device__ inline float tanhf_(float x){
  // 1 - 2/(1+e^{2x}); saturates correctly for |x| large via inf/0, no clamp
  float e = __expf(2.f * x);
  return 1.f - 2.f * frcp(1.f + e);
}
__device__ inline void unpack8(uint4 u, float* x){
  x[0]=bf_lo(u.x); x[1]=bf_hi(u.x); x[2]=bf_lo(u.y); x[3]=bf_hi(u.y);
  x[4]=bf_lo(u.z); x[5]=bf_hi(u.z); x[6]=bf_lo(u.w); x[7]=bf_hi(u.w);
}
__device__ inline f32x4 zero4(){ f32x4 v; v[0]=0.f; v[1]=0.f; v[2]=0.f; v[3]=0.f; return v; }
__device__ inline f32x4 splat4(float s){ f32x4 v; v[0]=s; v[1]=s; v[2]=s; v[3]=s; return v; }

__device__ inline void rowstats(const float* xr, float& mu, float& rstd){
  float s0=0.f, q0=0.f;
#pragma unroll
  for (int k = 0; k < 32; k++){ s0 += xr[k]; q0 += xr[k]*xr[k]; }
  s0 += __shfl_xor(s0, 1); q0 += __shfl_xor(q0, 1);
  s0 += __shfl_xor(s0, 2); q0 += __shfl_xor(q0, 2);
  mu = s0 * 0.0078125f;
  float var = q0 * 0.0078125f - mu*mu;
  rstd = rsqrtf(var + 1e-6f);
}

// ---------------------------------------------------------------------------
// Pack weights into MFMA B-fragment order.
// zWp: wss (K=128: k 0-63 = wss[.,0] (hprev), 64-127 = wss[.,1] (h)), N=256.
// wisp: wis K=128, N=256.  wocp: K=64, N=128.
// Fragment addr: ((kk*NCTG + ctg)*64 + lane)*8 + e, k = kk*32 + quad*8 + e,
// n = ctg*16 + l16.
// Also zeroes the diag handoff mailbox (in d_out scratch).
// ---------------------------------------------------------------------------
__global__ void pack_kernel(const float* __restrict__ w_is, const float* __restrict__ w_ss,
                            const float* __restrict__ b_is, const float* __restrict__ b_ss,
                            const float* __restrict__ w_oc, const float* __restrict__ w1,
                            const float* __restrict__ w2, const float* __restrict__ wh,
                            const float* __restrict__ ck,
                            ushort_t* __restrict__ zWp, ushort_t* __restrict__ wisp,
                            ushort_t* __restrict__ wocp,
                            float* __restrict__ zbias, float* __restrict__ w1T,
                            float* __restrict__ w2T, float* __restrict__ whT,
                            float* __restrict__ kw, uint_t* __restrict__ mb)
{
  int idx = blockIdx.x * 256 + threadIdx.x;
  if (idx < 131072){                        // zWp (wss): 4 ld x 32768
    int ld = idx >> 15; int r = idx & 32767;
    int e = r & 7, lane = (r >> 3) & 63, ctg = (r >> 9) & 15, kk = r >> 13;
    int k = kk*32 + ((lane >> 4) & 3)*8 + e;
    int n = ctg*16 + (lane & 15);
    float v;
    if (k < 64) v = w_ss[(((size_t)ld*2 + 0)*64 + k)*256 + n];
    else        v = w_ss[(((size_t)ld*2 + 1)*64 + (k-64))*256 + n];
    zWp[idx] = f2bf(v);
  } else if (idx < 262144){                 // wisp: 4 ld x 32768
    int r0 = idx - 131072;
    int ld = r0 >> 15; int r = r0 & 32767;
    int e = r & 7, lane = (r >> 3) & 63, ctg = (r >> 9) & 15, kk = r >> 13;
    int k = kk*32 + ((lane >> 4) & 3)*8 + e;
    int n = ctg*16 + (lane & 15);
    wisp[r0] = f2bf(w_is[((size_t)ld*128 + k)*256 + n]);
  } else if (idx < 294912){                 // wocp: 4 x 8192
    int r0 = idx - 262144;
    int ld = r0 >> 13; int r = r0 & 8191;
    int e = r & 7, lane = (r >> 3) & 63, ctg = (r >> 9) & 7, kk = (r >> 12) & 1;
    int k = kk*32 + ((lane >> 4) & 3)*8 + e;
    int n = ctg*16 + (lane & 15);
    wocp[r0] = f2bf(w_oc[((size_t)ld*64 + k)*128 + n]);
  } else if (idx < 295936){                 // fused z bias
    int r = idx - 294912;
    zbias[r] = b_is[r] + b_ss[r];
  } else if (idx < 300032){                 // w_out1^T (32,128)
    int r = idx - 295936;
    int c = r >> 7, k = r & 127;
    w1T[r] = w1[k*32 + c];
  } else if (idx < 301056){                 // w_out2^T (32,32)
    int r = idx - 300032;
    int c = r >> 5, k = r & 31;
    w2T[r] = w2[k*32 + c];
  } else if (idx < 309248){                 // w_head^T (256,32)
    int r = idx - 301056;
    int o = r >> 5, k = r & 31;
    whT[r] = wh[k*256 + o];
  } else if (idx < 312320){                 // 24 live conv taps x 128 ch
    int r = idx - 309248;
    int tau = r >> 7, ch = r & 127;
    int di, dj;
    if (tau < 21){ di = tau/7 - 3; dj = tau%7 - 3; } else { di = 0; dj = tau - 24; }
    kw[r] = ck[((di+3)*7 + (dj+3))*128 + ch];
  } else if (idx < (int)(312320 + MBW)){    // zero the mailbox (stamp 0 = empty)
    mb[idx - 312320] = 0u;
  }
}

// ---------------------------------------------------------------------------
// Masked 7x7 conv on the implicit skewed image. Output bf16 (B,64,127,128).
// One block per (b,i) row: 4 live im rows (mask keeps only di<=0) staged in
// LDS zero-padded, 24 per-channel weights in registers, loop over j.
// ---------------------------------------------------------------------------
__global__ __launch_bounds__(256) void conv_kernel(const float* __restrict__ im,
                const float* __restrict__ cb, const float* __restrict__ kw,
                ushort_t* __restrict__ out)
{
  __shared__ float ims[4][64];   // rows i-3..i, zero-padded for ii<0
  const int tid = threadIdx.x;
  const int b = blockIdx.x >> 6;
  const int i = blockIdx.x & 63;
  {
    int r = tid >> 6, c = tid & 63;
    int ii = i - 3 + r;
    ims[r][c] = (ii >= 0) ? im[(b*64 + ii)*64 + c] : 0.f;
  }
  const int ch = tid & 127;
  const int jh = tid >> 7;       // 0/1: even/odd j
  float kwreg[24];
#pragma unroll
  for (int tau = 0; tau < 24; tau++) kwreg[tau] = kw[tau*128 + ch];
  const float cbv = cb[ch];
  __syncthreads();
  ushort_t* orow = out + ((size_t)(b*64 + i)*N2)*128 + ch;
#pragma unroll 1
  for (int jt = 0; jt < 64; jt++){
    int j = jt*2 + jh;
    if (j >= N2) break;
    int base = j - i;
    float acc = cbv;
#pragma unroll
    for (int tau = 0; tau < 24; tau++){
      int di = (tau < 21) ? (tau/7 - 3) : 0;
      int dj = (tau < 21) ? (tau%7 - 3) : (tau - 24);
      int jx = base + dj - di;
      int r = di + 3;
      if (jx >= 0 && jx < 64)
        acc += ims[r][jx] * kwreg[tau];
    }
    orow[(size_t)j*128] = f2bf(acc);
  }
}

// ---------------------------------------------------------------------------
// write_frags: XN (64x128 bf16 tile, stride 136) -> global fragment file
// (16 KB per (b,j) tile) in diag's A-fragment order.
// ---------------------------------------------------------------------------
__device__ inline void write_frags(const ushort_t* __restrict__ XN,
                                   ushort_t* __restrict__ dst, int tid){
  int lane = tid & 63, kkq = tid >> 6;
  int quad = (lane >> 4) & 3, l16 = lane & 15;
#pragma unroll
  for (int rt = 0; rt < 4; rt++){
    uint4 v = *(const uint4*)&XN[(size_t)(rt*16 + l16)*136 + kkq*32 + quad*8];
    *(uint4*)(dst + (size_t)((kkq*4 + rt)*64 + lane)*8) = v;
  }
}

// LN a 32-elem row-quarter into XN, packed-bf16 + vector LDS writes.
__device__ inline void ln_to_XN(ushort_t* __restrict__ XN, int row, int lq,
                                const float* xr, float mu, float rstd,
                                const float* __restrict__ ln_s,
                                const float* __restrict__ ln_b, int ld){
  uint_t o[16];
#pragma unroll
  for (int k2 = 0; k2 < 16; k2++){
    int c = lq*32 + 2*k2;
    float a = (xr[2*k2]   - mu)*rstd*ln_s[ld*128 + c]     + ln_b[ld*128 + c];
    float b = (xr[2*k2+1] - mu)*rstd*ln_s[ld*128 + c + 1] + ln_b[ld*128 + c + 1];
    o[k2] = cvt_pk_bf16(a, b);
  }
  uint4* dst = (uint4*)&XN[(size_t)row*136 + lq*32];
#pragma unroll
  for (int q = 0; q < 4; q++) dst[q] = make_uint4(o[q*4], o[q*4+1], o[q*4+2], o[q*4+3]);
}

// ---------------------------------------------------------------------------
// stage0: xn = LN(Xbuf; layer 0, both dirs) -> xnf fragment files.
// LDS = XN only (17.4 KB) -> high occupancy.
// ---------------------------------------------------------------------------
__global__ __launch_bounds__(256) void stage0_kernel(
    int lnlyr, const ushort_t* __restrict__ Xbuf,
    const float* __restrict__ ln_s, const float* __restrict__ ln_b,
    ushort_t* __restrict__ xnfL, ushort_t* __restrict__ xnfR)
{
  __shared__ __align__(16) ushort_t XN[64*136];    // 17408 B

  const int tid = threadIdx.x;
  const int bj = blockIdx.x;
  const int b = bj / 127, j = bj - b*127;
  const int row = tid >> 2, lq = tid & 3;

  float xr[32];
  {
    const uint4* p = (const uint4*)(Xbuf + ((size_t)(b*64 + row)*N2 + j)*128 + lq*32);
    unpack8(p[0], xr); unpack8(p[1], xr+8); unpack8(p[2], xr+16); unpack8(p[3], xr+24);
  }
  float mu, rstd;
  rowstats(xr, mu, rstd);

  ln_to_XN(XN, row, lq, xr, mu, rstd, ln_s, ln_b, lnlyr*2 + 0);
  __syncthreads();
  write_frags(XN, xnfL + (size_t)bj*8192, tid);
  __syncthreads();
  ln_to_XN(XN, row, lq, xr, mu, rstd, ln_s, ln_b, lnlyr*2 + 1);
  __syncthreads();
  write_frags(XN, xnfR + (size_t)bj*8192, tid);
}

// ---------------------------------------------------------------------------
// stage12 (modes 1,2; 2032 blocks = (b,j)).
// mode 1: X' = [hnL@wocL+bocL+LN(X;wl,L)] + shift_m[...R]; X'->Xbuf (in place,
//         own j-slice only); then LN(X'; lnlyr both dirs) -> xnf frags.
// mode 2: like mode 1 but stops after writing X' (the head input).
// hn MFMA A-fragments are loaded DIRECTLY global->reg (8 contiguous bf16,
// 16B-aligned), issued before the barrier so latency hides under LN.
// No XNh staging -> LDS 51.2 KB -> 3 blocks/CU (was 2).
// ---------------------------------------------------------------------------
__global__ __launch_bounds__(256, 2) void stage12_kernel(
    int mode, int woclyr, int lnlyr,
    ushort_t* __restrict__ Xbuf,
    const ushort_t* __restrict__ hnL, const ushort_t* __restrict__ hnR,
    const ushort_t* __restrict__ wocp, const float* __restrict__ b_oc,
    const float* __restrict__ ln_s, const float* __restrict__ ln_b,
    ushort_t* __restrict__ xnfL, ushort_t* __restrict__ xnfR)
{
  __shared__ __align__(16) float Xout[64*132];     // 33792 B
  __shared__ __align__(16) ushort_t XN[64*136];    // 17408 B  (total 51200)

  const int tid = threadIdx.x;
  const int bj = blockIdx.x;
  const int b = bj / 127, j = bj - b*127;
  const int w = tid >> 6, lane = tid & 63, quad = (lane >> 4) & 3, l16 = lane & 15;
  const int row = tid >> 2, lq = tid & 3;

  // this thread's X row-quarter (bf16 -> fp32 regs)
  float xr[32];
  {
    const uint4* p = (const uint4*)(Xbuf + ((size_t)(b*64 + row)*N2 + j)*128 + lq*32);
    unpack8(p[0], xr); unpack8(p[1], xr+8); unpack8(p[2], xr+16); unpack8(p[3], xr+24);
  }
  float mu, rstd;
  rowstats(xr, mu, rstd);

  // ---- woc epilogues for both directions, combined with m-shift ----
#pragma unroll 1
  for (int s = 0; s < 2; s++){
    const int ld = woclyr*2 + s;
    const ushort_t* hp = s ? hnR : hnL;
    // A-fragments direct global->reg: row rt*16+l16, cols kk*32+quad*8..+8
    s8bf ha[2][4];
#pragma unroll
    for (int kk = 0; kk < 2; kk++)
#pragma unroll
      for (int rt = 0; rt < 4; rt++)
        ha[kk][rt] = *(const s8bf*)(hp +
            ((size_t)(b*64 + rt*16 + l16)*N2 + j)*64 + kk*32 + quad*8);
    ln_to_XN(XN, row, lq, xr, mu, rstd, ln_s, ln_b, ld);   // residual xn
    __syncthreads();
    s8bf bw[2][2];
#pragma unroll
    for (int kk = 0; kk < 2; kk++)
#pragma unroll
      for (int jt = 0; jt < 2; jt++)
        bw[kk][jt] = *(const s8bf*)(wocp + (size_t)ld*8192 + (size_t)(((kk*8 + (2*w + jt))*64 + lane)*8));
    f32x4 a2[4][2];
#pragma unroll
    for (int rt = 0; rt < 4; rt++){ a2[rt][0] = zero4(); a2[rt][1] = zero4(); }
#pragma unroll
    for (int kk = 0; kk < 2; kk++)
#pragma unroll
      for (int rt = 0; rt < 4; rt++){
#pragma unroll
        for (int jt = 0; jt < 2; jt++)
          a2[rt][jt] = __builtin_amdgcn_mfma_f32_16x16x32_bf16(ha[kk][rt], bw[kk][jt], a2[rt][jt], 0, 0, 0);
      }
    const float bv0 = b_oc[ld*128 + 32*w + l16];
    const float bv1 = b_oc[ld*128 + 32*w + 16 + l16];
#pragma unroll
    for (int rt = 0; rt < 4; rt++)
#pragma unroll
      for (int jt = 0; jt < 2; jt++){
        int col = 32*w + 16*jt + l16;
        float bv = jt ? bv1 : bv0;
#pragma unroll
        for (int r = 0; r < 4; r++){
          int rr = rt*16 + quad*4 + r;
          float v = a2[rt][jt][r] + bv + bf2f(XN[(size_t)rr*136 + col]);
          if (s == 0) Xout[(size_t)rr*132 + col] = v;
          else if (rr < 63) Xout[(size_t)(rr + 1)*132 + col] += v;  // m-shift; row 0 = left only
        }
      }
    __syncthreads();
  }

  // ---- write combined X back to Xbuf (own j-slice; reads all done) ----
  float xo[32];
#pragma unroll
  for (int k = 0; k < 32; k++) xo[k] = Xout[(size_t)row*132 + lq*32 + k];
  {
    uint_t o[16];
#pragma unroll
    for (int k = 0; k < 16; k++) o[k] = cvt_pk_bf16(xo[2*k], xo[2*k + 1]);
    uint4* dst = (uint4*)(Xbuf + ((size_t)(b*64 + row)*N2 + j)*128 + lq*32);
#pragma unroll
    for (int q2 = 0; q2 < 4; q2++) dst[q2] = make_uint4(o[q2*4], o[q2*4+1], o[q2*4+2], o[q2*4+3]);
  }
  if (mode == 2) return;

  // ---- LN for the next layer -> fragment files ----
  float mu2, rstd2;
  rowstats(xo, mu2, rstd2);
  ln_to_XN(XN, row, lq, xo, mu2, rstd2, ln_s, ln_b, lnlyr*2 + 0);
  __syncthreads();
  write_frags(XN, xnfL + (size_t)bj*8192, tid);
  __syncthreads();
  ln_to_XN(XN, row, lq, xo, mu2, rstd2, ln_s, ln_b, lnlyr*2 + 1);
  __syncthreads();
  write_frags(XN, xnfR + (size_t)bj*8192, tid);
}

// ---------------------------------------------------------------------------
// Diagonal LSTM recurrence, row-split 4 ways: 128 blocks = (d, b, g) with
// row group g owning rows 16g..16g+15.  256 threads / 4 waves; wave w owns
// h-col group w (16 cols x 4 gates).  Cross-group coupling is only the
// one-row hprev shift, handled by a stamped mailbox in d_out scratch:
//   word[col] = (stamp16 << 16) | h_bf16,  stamp = layer*127 + t + 1.
// Producer lanes (quad==3, r==3 hold row 15) fire agent-scope stores from
// registers during the gate phase -- no vmcnt drain, no ordering fence
// (stamp and data share the word, u32 stores are atomic).  Consumer polls
// its 64 words (load issued at loop top, checked after zxa -> MALL latency
// hidden).  Producers never wait on consumers -> no deadlock.
// LDS A double-buffered -> ONE barrier per step.  (Proven 162us/dispatch
// structure.)
// ---------------------------------------------------------------------------
__global__ __launch_bounds__(256, 1) void diag_kernel(
    const ushort_t* __restrict__ xnfL, const ushort_t* __restrict__ xnfR,
    ushort_t* __restrict__ hnL, ushort_t* __restrict__ hnR,
    const ushort_t* __restrict__ zWp, const ushort_t* __restrict__ wisp,
    const float* __restrict__ zbias, const float* __restrict__ h0, int layer,
    uint_t* __restrict__ mb)
{
  __shared__ ushort_t A[2][16][136];  // [buf][row][hprev(0:64)|h(64:128)], +8 pad

  const int tid = threadIdx.x;
  const int g = blockIdx.x & 3;           // row group
  const int b = (blockIdx.x >> 2) & 15;
  const int d = blockIdx.x >> 6;
  const int ld = layer*2 + d;
  const ushort_t* xnf = d ? xnfR : xnfL;
  ushort_t* hp = d ? hnR : hnL;

  const int w = tid >> 6;             // wave = col group (16 cols per gate)
  const int lane = tid & 63;
  const int quad = lane >> 4;
  const int l16 = lane & 15;
  const int cg = w*16 + l16;

  // B fragments: all 4 gates of this wave's col group, wis + wss
  s8bf bss[4][4], bis[4][4];
#pragma unroll
  for (int kk = 0; kk < 4; kk++)
#pragma unroll
    for (int ct = 0; ct < 4; ct++){
      size_t fo = (size_t)(((kk*16 + (w + 4*ct))*64 + lane)*8);
      bss[kk][ct] = *(const s8bf*)(zWp  + (size_t)ld*32768 + fo);
      bis[kk][ct] = *(const s8bf*)(wisp + (size_t)ld*32768 + fo);
    }
  float zb[4];
#pragma unroll
  for (int ct = 0; ct < 4; ct++) zb[ct] = zbias[ld*256 + ct*64 + cg];

  float c_reg[4] = {0.f, 0.f, 0.f, 0.f};

  { // init both A buffers: h carry = h0 broadcast; hprev = h0 (global row 0 -> 0)
    int r2 = tid >> 4, q8 = tid & 15;
    const float* h0p = h0 + ld*64;
#pragma unroll
    for (int k = 0; k < 8; k++){
      int c = q8*8 + k;
      ushort_t hb = f2bf(h0p[c & 63]);
      ushort_t v;
      if (c < 64) v = (g == 0 && r2 == 0) ? (ushort_t)0 : hb;
      else        v = hb;
      A[0][r2][c] = v;
      A[1][r2][c] = v;
    }
  }

  // xf = xn(0) fragments (this group's 16-row tile); zxa(0); prefetch xn(1)
  const int stp8 = d ? -8192 : 8192;
  const ushort_t* xbase = xnf + ((size_t)b*127 + (d ? 126 : 0))*8192;
  uint4 xf[4];
#pragma unroll
  for (int kk = 0; kk < 4; kk++)
    xf[kk] = *(const uint4*)(xbase + (size_t)((kk*4 + g)*64 + lane)*8);

  f32x4 acc[4];
#pragma unroll
  for (int ct = 0; ct < 4; ct++) acc[ct] = splat4(zb[ct]);
#pragma unroll
  for (int kk = 0; kk < 4; kk++){
    s8bf a = *(const s8bf*)&xf[kk];
#pragma unroll
    for (int ct = 0; ct < 4; ct++)
      acc[ct] = __builtin_amdgcn_mfma_f32_16x16x32_bf16(a, bis[kk][ct], acc[ct], 0, 0, 0);
  }
  const ushort_t* pfp = xbase + stp8;   // next prefetch tile (t=1)
#pragma unroll
  for (int kk = 0; kk < 4; kk++)
    xf[kk] = *(const uint4*)(pfp + (size_t)((kk*4 + g)*64 + lane)*8);
  pfp += stp8;

  // running hn store pointer (lane base row = g*16 + quad*4, col cg)
  const int dj64 = d ? -64 : 64;
  ushort_t* hlane = hp + ((size_t)(b*64 + g*16 + quad*4)*N2 + (d ? 126 : 0))*64 + cg;

  // mailbox plumbing: link g = boundary below group g (rows 16g+15 / 16g+16)
  const int bd = b*2 + d;
  uint_t* mbOut = mb + ((size_t)(bd*3 + g)*127)*64;                 // g<3
  const uint_t* mbIn = mb + ((size_t)(bd*3 + (g > 0 ? g - 1 : 0))*127)*64;
  const uint_t stampBase = (uint_t)layer * 127u;
  const bool isProd = (g < 3);
  const bool isCons = (g > 0) && (w == 1);   // full wave: 1 col per lane

  __syncthreads();  // A init visible

#pragma unroll 1
  for (int t = 0; t < 127; t++){
    const int pr = t & 1, pn = pr ^ 1;
    const uint_t stamp = stampBase + (uint_t)t + 1u;
    const bool doFetch = isCons && (t < 126);

    // early poll: issued now, first checked after zxa (MALL latency hidden)
    uint_t pv = 0;
    if (doFetch)
      pv = __hip_atomic_load(mbIn + (size_t)t*64 + lane,
                             __ATOMIC_RELAXED, __HIP_MEMORY_SCOPE_AGENT);

    // ---- phase A: acc += [hprev|h] @ wss ----
#pragma unroll
    for (int kk = 0; kk < 4; kk++){
      s8bf af = *(const s8bf*)&A[pr][l16][kk*32 + quad*8];
#pragma unroll
      for (int ct = 0; ct < 4; ct++)
        acc[ct] = __builtin_amdgcn_mfma_f32_16x16x32_bf16(af, bss[kk][ct], acc[ct], 0, 0, 0);
    }

    // ---- phase B: gates (VALU) + fire-and-forget boundary publish ----
#pragma unroll
    for (int r = 0; r < 4; r++){
      float fg = sigm(acc[0][r]);
      float ig = sigm(acc[1][r]);
      float og = sigm(acc[2][r]);
      float gg = tanhf_(acc[3][r]);
      float cn = fg*c_reg[r] + ig*gg;
      c_reg[r] = cn;
      float hn = og * tanhf_(cn);
      int rr = quad*4 + r;
      ushort_t hb = f2bf(hn);
      A[pn][rr][64 + cg] = hb;
      if (rr < 15) A[pn][rr + 1][cg] = hb;
      hlane[(size_t)r*8128] = hb;
      if (r == 3 && isProd && quad == 3 && t < 126)   // row 15 -> mailbox
        __hip_atomic_store(mbOut + (size_t)t*64 + cg,
                           (stamp << 16) | (uint_t)hb,
                           __ATOMIC_RELAXED, __HIP_MEMORY_SCOPE_AGENT);
    }
    hlane += dj64;

    // ---- phase B: zxa(t+1) = xn(t+1)@wis + zbias ----
    if (t < 126){
#pragma unroll
      for (int ct = 0; ct < 4; ct++) acc[ct] = splat4(zb[ct]);
#pragma unroll
      for (int kk = 0; kk < 4; kk++){
        s8bf a = *(const s8bf*)&xf[kk];
#pragma unroll
        for (int ct = 0; ct < 4; ct++)
          acc[ct] = __builtin_amdgcn_mfma_f32_16x16x32_bf16(a, bis[kk][ct], acc[ct], 0, 0, 0);
      }
      if (t < 125){
#pragma unroll
        for (int kk = 0; kk < 4; kk++)
          xf[kk] = *(const uint4*)(pfp + (size_t)((kk*4 + g)*64 + lane)*8);
        pfp += stp8;
      }
    }

    // ---- consumer: check stamped words; spin only while lead establishes
    if (doFetch){
      while (!__all((pv >> 16) == stamp))
        pv = __hip_atomic_load(mbIn + (size_t)t*64 + lane,
                               __ATOMIC_RELAXED, __HIP_MEMORY_SCOPE_AGENT);
      A[pn][0][lane] = (ushort_t)(pv & 0xffffu);   // neighbor h(t) -> hprev
    }

    __syncthreads(); // new h/hprev (buffer pn) visible for next phase A
  }
}

// ---------------------------------------------------------------------------
// Head: unskew + (128->32)->(32->32)->(32->256), fp32 vector math.
// L1 k-loop chunked 4x32 so the weight array is 32 floats (was 128 VGPRs).
// ---------------------------------------------------------------------------
__global__ __launch_bounds__(256) void head_kernel(
    const ushort_t* __restrict__ xfin,
    const float* __restrict__ w1T, const float* __restrict__ b1,
    const float* __restrict__ w2T, const float* __restrict__ b2,
    const float* __restrict__ whT, const float* __restrict__ bh,
    float* __restrict__ out)
{
  __shared__ float xf[64][132];
  __shared__ float v1[64][36];
  __shared__ float v2[64][36];
  int tid = threadIdx.x;
  int b = blockIdx.x >> 6, i = blockIdx.x & 63;
  {
    int jj = tid >> 2, q = tid & 3;
    size_t base = ((size_t)(b*64 + i)*N2 + (i + jj))*128 + q*32;  // unskew
    const uint4* pL = (const uint4*)(xfin + base);
    float x[32];
    unpack8(pL[0], x); unpack8(pL[1], x+8); unpack8(pL[2], x+16); unpack8(pL[3], x+24);
#pragma unroll
    for (int k = 0; k < 32; k++) xf[jj][q*32 + k] = x[k];
  }
  __syncthreads();
  {
    int c1 = tid & 31, jg = tid >> 5;
    float accv[8];
#pragma unroll
    for (int q = 0; q < 8; q++) accv[q] = b1[c1];
#pragma unroll 1
    for (int kc = 0; kc < 4; kc++){
      float wr[32];
      const float4* wp = (const float4*)(w1T + c1*128 + kc*32);
#pragma unroll
      for (int kk = 0; kk < 8; kk++) ((float4*)wr)[kk] = wp[kk];
#pragma unroll
      for (int jj2 = 0; jj2 < 8; jj2++){
        int jr = jg*8 + jj2;
        float a0=0.f,a1=0.f,a2=0.f,a3=0.f;
#pragma unroll
        for (int kk = 0; kk < 8; kk++){
          float4 xv = *(const float4*)&xf[jr][kc*32 + kk*4];
          a0 += xv.x*wr[kk*4]; a1 += xv.y*wr[kk*4+1]; a2 += xv.z*wr[kk*4+2]; a3 += xv.w*wr[kk*4+3];
        }
        accv[jj2] += (a0+a1)+(a2+a3);
      }
    }
#pragma unroll
    for (int jj2 = 0; jj2 < 8; jj2++) v1[jg*8 + jj2][c1] = accv[jj2];
  }
  __syncthreads();
  {
    int c2 = tid & 31, jg = tid >> 5;
    float wr[32];
    const float4* wp = (const float4*)(w2T + c2*32);
#pragma unroll
    for (int kk = 0; kk < 8; kk++) ((float4*)wr)[kk] = wp[kk];
#pragma unroll 1
    for (int jj2 = 0; jj2 < 8; jj2++){
      int jr = jg*8 + jj2;
      float a0=0.f,a1=0.f,a2=0.f,a3=0.f;
#pragma unroll
      for (int kk = 0; kk < 8; kk++){
        float4 xv = *(const float4*)&v1[jr][kk*4];
        a0 += xv.x*wr[kk*4]; a1 += xv.y*wr[kk*4+1]; a2 += xv.z*wr[kk*4+2]; a3 += xv.w*wr[kk*4+3];
      }
      v2[jr][c2] = b2[c2] + (a0+a1)+(a2+a3);
    }
  }
  __syncthreads();
  {
    int o = tid;
    float wr[32];
    const float4* wp = (const float4*)(whT + o*32);
#pragma unroll
    for (int kk = 0; kk < 8; kk++) ((float4*)wr)[kk] = wp[kk];
    float bo = bh[o];
#pragma unroll 1
    for (int jr = 0; jr < 64; jr++){
      float a0=0.f,a1=0.f,a2=0.f,a3=0.f;
#pragma unroll
      for (int kk = 0; kk < 8; kk++){
        float4 xv = *(const float4*)&v2[jr][kk*4];
        a0 += xv.x*wr[kk*4]; a1 += xv.y*wr[kk*4+1]; a2 += xv.z*wr[kk*4+2]; a3 += xv.w*wr[kk*4+3];
      }
      out[(((size_t)b*64 + i)*64 + jr)*256 + o] = bo + (a0+a1)+(a2+a3);
    }
  }
}

// ---------------------------------------------------------------------------
extern "C" void kernel_launch(void* const* d_in, const int* in_sizes, int n_in,
                              void* d_out, int out_size, void* d_ws, size_t ws_size,
                              hipStream_t stream)
{
  const float* im   = (const float*)d_in[0];
  const float* ck   = (const float*)d_in[1];
  const float* cb   = (const float*)d_in[2];
  const float* ln_s = (const float*)d_in[3];
  const float* ln_b = (const float*)d_in[4];
  const float* w_is = (const float*)d_in[5];
  const float* b_is = (const float*)d_in[6];
  const float* w_ss = (const float*)d_in[7];
  const float* b_ss = (const float*)d_in[8];
  const float* w_oc = (const float*)d_in[9];
  const float* b_oc = (const float*)d_in[10];
  const float* h0   = (const float*)d_in[11];
  const float* w1   = (const float*)d_in[12];
  const float* b1   = (const float*)d_in[13];
  const float* w2   = (const float*)d_in[14];
  const float* b2   = (const float*)d_in[15];
  const float* wh   = (const float*)d_in[16];
  const float* bh   = (const float*)d_in[17];

  // Workspace layout: within Round-1's proven footprint (mailbox lives in
  // d_out, which is dead scratch until head_kernel writes it).
  ushort_t* Xbuf = (ushort_t*)d_ws;        // X0 -> X1 (aliased) -> xfin
  ushort_t* xnfL = Xbuf + ACT;             // xn fragment files (per layer, overwritten)
  ushort_t* xnfR = xnfL + ACT;
  ushort_t* hnL  = xnfR + ACT;
  ushort_t* hnR  = hnL + HNE;
  ushort_t* zWp  = hnR + HNE;              // wss frags  (131072 el)
  ushort_t* wisp = zWp + 131072;           // wis frags  (131072 el)
  ushort_t* wocp = wisp + 131072;          // woc frags  (32768 el)
  float* zbias = (float*)(wocp + 32768);
  float* w1T   = zbias + 1024;
  float* w2T   = w1T + 4096;
  float* whT   = w2T + 1024;
  float* kw    = whT + 8192;
  uint_t* mb   = (uint_t*)d_out;           // stamped handoff mailbox (3.1 MB)

  pack_kernel<<<4268, 256, 0, stream>>>(w_is, w_ss, b_is, b_ss, w_oc, w1, w2, wh, ck,
                                        zWp, wisp, wocp, zbias, w1T, w2T, whT, kw, mb);
  conv_kernel<<<1024, 256, 0, stream>>>(im, cb, kw, Xbuf);
  stage0_kernel<<<2032, 256, 0, stream>>>(0, Xbuf, ln_s, ln_b, xnfL, xnfR);
  diag_kernel<<<128, 256, 0, stream>>>(xnfL, xnfR, hnL, hnR, zWp, wisp, zbias, h0, 0, mb);
  stage12_kernel<<<2032, 256, 0, stream>>>(1, 0, 1, Xbuf, hnL, hnR,
                                           wocp, b_oc, ln_s, ln_b, xnfL, xnfR);
  diag_kernel<<<128, 256, 0, stream>>>(xnfL, xnfR, hnL, hnR, zWp, wisp, zbias, h0, 1, mb);
  stage12_kernel<<<2032, 256, 0, stream>>>(2, 1, 0, Xbuf, hnL, hnR,
                                           wocp, b_oc, ln_s, ln_b, xnfL, xnfR);
  head_kernel<<<1024, 256, 0, stream>>>(Xbuf, w1T, b1, w2T, b2, whT, bh, (float*)d_out);
}

// Round 11
// 668.799 us; speedup vs baseline: 1.1250x; 1.1250x over previous
//
#include <hip/hip_runtime.h>

typedef unsigned short ushort_t;
typedef unsigned int uint_t;
typedef __attribute__((ext_vector_type(8))) short s8bf;   // 8 x bf16 MFMA fragment
typedef __attribute__((ext_vector_type(4))) float f32x4;  // MFMA accumulator

#define N2 127
#define ACT ((size_t)16*64*127*128)     // activation elements (bf16)
#define HNE ((size_t)16*64*127*64)      // hn elements (bf16)
#define MBW ((size_t)32*3*127*64)       // mailbox words (u32), lives in d_out

__device__ inline float bf_lo(uint_t v){ return __uint_as_float(v << 16); }
__device__ inline float bf_hi(uint_t v){ return __uint_as_float(v & 0xffff0000u); }
__device__ inline ushort_t f2bf(float f){
  uint_t u = __float_as_uint(f);
  uint_t r = ((u >> 16) & 1u) + 0x7fffu;  // RNE
  return (ushort_t)((u + r) >> 16);
}
// packed RNE f32x2 -> bf16x2 (same rounding as f2bf, 1 instr instead of ~10)
__device__ inline uint_t cvt_pk_bf16(float lo, float hi){
  uint_t r;
  asm("v_cvt_pk_bf16_f32 %0, %1, %2" : "=v"(r) : "v"(lo), "v"(hi));
  return r;
}
__device__ inline float bf2f(ushort_t h){ return __uint_as_float(((uint_t)h) << 16); }
__device__ inline float frcp(float x){ return __builtin_amdgcn_rcpf(x); }
__device__ inline float sigm(float x){ return frcp(1.f + __expf(-x)); }
__device__ inline float tanhf_(float x){
  // 1 - 2/(1+e^{2x}); saturates correctly for |x| large via inf/0, no clamp
  float e = __expf(2.f * x);
  return 1.f - 2.f * frcp(1.f + e);
}
__device__ inline void unpack8(uint4 u, float* x){
  x[0]=bf_lo(u.x); x[1]=bf_hi(u.x); x[2]=bf_lo(u.y); x[3]=bf_hi(u.y);
  x[4]=bf_lo(u.z); x[5]=bf_hi(u.z); x[6]=bf_lo(u.w); x[7]=bf_hi(u.w);
}
__device__ inline f32x4 zero4(){ f32x4 v; v[0]=0.f; v[1]=0.f; v[2]=0.f; v[3]=0.f; return v; }
__device__ inline f32x4 splat4(float s){ f32x4 v; v[0]=s; v[1]=s; v[2]=s; v[3]=s; return v; }

// 4 threads/row, 32 elems each
__device__ inline void rowstats(const float* xr, float& mu, float& rstd){
  float s0=0.f, q0=0.f;
#pragma unroll
  for (int k = 0; k < 32; k++){ s0 += xr[k]; q0 += xr[k]*xr[k]; }
  s0 += __shfl_xor(s0, 1); q0 += __shfl_xor(q0, 1);
  s0 += __shfl_xor(s0, 2); q0 += __shfl_xor(q0, 2);
  mu = s0 * 0.0078125f;
  float var = q0 * 0.0078125f - mu*mu;
  rstd = rsqrtf(var + 1e-6f);
}

// 8 threads/row, 16 elems each
__device__ inline void rowstats16(const float* xr, float& mu, float& rstd){
  float s0=0.f, q0=0.f;
#pragma unroll
  for (int k = 0; k < 16; k++){ s0 += xr[k]; q0 += xr[k]*xr[k]; }
  s0 += __shfl_xor(s0, 1); q0 += __shfl_xor(q0, 1);
  s0 += __shfl_xor(s0, 2); q0 += __shfl_xor(q0, 2);
  s0 += __shfl_xor(s0, 4); q0 += __shfl_xor(q0, 4);
  mu = s0 * 0.0078125f;
  float var = q0 * 0.0078125f - mu*mu;
  rstd = rsqrtf(var + 1e-6f);
}

// ---------------------------------------------------------------------------
// Pack weights into MFMA B-fragment order.
// zWp: wss (K=128: k 0-63 = wss[.,0] (hprev), 64-127 = wss[.,1] (h)), N=256.
// wisp: wis K=128, N=256.  wocp: K=64, N=128.
// Fragment addr: ((kk*NCTG + ctg)*64 + lane)*8 + e, k = kk*32 + quad*8 + e,
// n = ctg*16 + l16.
// Also zeroes the diag handoff mailbox (in d_out scratch).
// ---------------------------------------------------------------------------
__global__ void pack_kernel(const float* __restrict__ w_is, const float* __restrict__ w_ss,
                            const float* __restrict__ b_is, const float* __restrict__ b_ss,
                            const float* __restrict__ w_oc, const float* __restrict__ w1,
                            const float* __restrict__ w2, const float* __restrict__ wh,
                            const float* __restrict__ ck,
                            ushort_t* __restrict__ zWp, ushort_t* __restrict__ wisp,
                            ushort_t* __restrict__ wocp,
                            float* __restrict__ zbias, float* __restrict__ w1T,
                            float* __restrict__ w2T, float* __restrict__ whT,
                            float* __restrict__ kw, uint_t* __restrict__ mb)
{
  int idx = blockIdx.x * 256 + threadIdx.x;
  if (idx < 131072){                        // zWp (wss): 4 ld x 32768
    int ld = idx >> 15; int r = idx & 32767;
    int e = r & 7, lane = (r >> 3) & 63, ctg = (r >> 9) & 15, kk = r >> 13;
    int k = kk*32 + ((lane >> 4) & 3)*8 + e;
    int n = ctg*16 + (lane & 15);
    float v;
    if (k < 64) v = w_ss[(((size_t)ld*2 + 0)*64 + k)*256 + n];
    else        v = w_ss[(((size_t)ld*2 + 1)*64 + (k-64))*256 + n];
    zWp[idx] = f2bf(v);
  } else if (idx < 262144){                 // wisp: 4 ld x 32768
    int r0 = idx - 131072;
    int ld = r0 >> 15; int r = r0 & 32767;
    int e = r & 7, lane = (r >> 3) & 63, ctg = (r >> 9) & 15, kk = r >> 13;
    int k = kk*32 + ((lane >> 4) & 3)*8 + e;
    int n = ctg*16 + (lane & 15);
    wisp[r0] = f2bf(w_is[((size_t)ld*128 + k)*256 + n]);
  } else if (idx < 294912){                 // wocp: 4 x 8192
    int r0 = idx - 262144;
    int ld = r0 >> 13; int r = r0 & 8191;
    int e = r & 7, lane = (r >> 3) & 63, ctg = (r >> 9) & 7, kk = (r >> 12) & 1;
    int k = kk*32 + ((lane >> 4) & 3)*8 + e;
    int n = ctg*16 + (lane & 15);
    wocp[r0] = f2bf(w_oc[((size_t)ld*64 + k)*128 + n]);
  } else if (idx < 295936){                 // fused z bias
    int r = idx - 294912;
    zbias[r] = b_is[r] + b_ss[r];
  } else if (idx < 300032){                 // w_out1^T (32,128)
    int r = idx - 295936;
    int c = r >> 7, k = r & 127;
    w1T[r] = w1[k*32 + c];
  } else if (idx < 301056){                 // w_out2^T (32,32)
    int r = idx - 300032;
    int c = r >> 5, k = r & 31;
    w2T[r] = w2[k*32 + c];
  } else if (idx < 309248){                 // w_head^T (256,32)
    int r = idx - 301056;
    int o = r >> 5, k = r & 31;
    whT[r] = wh[k*256 + o];
  } else if (idx < 312320){                 // 24 live conv taps x 128 ch
    int r = idx - 309248;
    int tau = r >> 7, ch = r & 127;
    int di, dj;
    if (tau < 21){ di = tau/7 - 3; dj = tau%7 - 3; } else { di = 0; dj = tau - 24; }
    kw[r] = ck[((di+3)*7 + (dj+3))*128 + ch];
  } else if (idx < (int)(312320 + MBW)){    // zero the mailbox (stamp 0 = empty)
    mb[idx - 312320] = 0u;
  }
}

// ---------------------------------------------------------------------------
// Masked 7x7 conv on the implicit skewed image. Output bf16 (B,64,127,128).
// One block per (b,i) row: 4 live im rows (mask keeps only di<=0) staged in
// LDS zero-padded, 24 per-channel weights in registers, loop over j.
// ---------------------------------------------------------------------------
__global__ __launch_bounds__(256) void conv_kernel(const float* __restrict__ im,
                const float* __restrict__ cb, const float* __restrict__ kw,
                ushort_t* __restrict__ out)
{
  __shared__ float ims[4][64];   // rows i-3..i, zero-padded for ii<0
  const int tid = threadIdx.x;
  const int b = blockIdx.x >> 6;
  const int i = blockIdx.x & 63;
  {
    int r = tid >> 6, c = tid & 63;
    int ii = i - 3 + r;
    ims[r][c] = (ii >= 0) ? im[(b*64 + ii)*64 + c] : 0.f;
  }
  const int ch = tid & 127;
  const int jh = tid >> 7;       // 0/1: even/odd j
  float kwreg[24];
#pragma unroll
  for (int tau = 0; tau < 24; tau++) kwreg[tau] = kw[tau*128 + ch];
  const float cbv = cb[ch];
  __syncthreads();
  ushort_t* orow = out + ((size_t)(b*64 + i)*N2)*128 + ch;
#pragma unroll 1
  for (int jt = 0; jt < 64; jt++){
    int j = jt*2 + jh;
    if (j >= N2) break;
    int base = j - i;
    float acc = cbv;
#pragma unroll
    for (int tau = 0; tau < 24; tau++){
      int di = (tau < 21) ? (tau/7 - 3) : 0;
      int dj = (tau < 21) ? (tau%7 - 3) : (tau - 24);
      int jx = base + dj - di;
      int r = di + 3;
      if (jx >= 0 && jx < 64)
        acc += ims[r][jx] * kwreg[tau];
    }
    orow[(size_t)j*128] = f2bf(acc);
  }
}

// ---------------------------------------------------------------------------
// write_frags (256-thread): XN (64x128 bf16 tile, stride 136) -> global
// fragment file (16 KB per (b,j) tile) in diag's A-fragment order.
// ---------------------------------------------------------------------------
__device__ inline void write_frags(const ushort_t* __restrict__ XN,
                                   ushort_t* __restrict__ dst, int tid){
  int lane = tid & 63, kkq = tid >> 6;
  int quad = (lane >> 4) & 3, l16 = lane & 15;
#pragma unroll
  for (int rt = 0; rt < 4; rt++){
    uint4 v = *(const uint4*)&XN[(size_t)(rt*16 + l16)*136 + kkq*32 + quad*8];
    *(uint4*)(dst + (size_t)((kkq*4 + rt)*64 + lane)*8) = v;
  }
}

// write_frags (512-thread): 8 wave-groups, 2 frag rows each
__device__ inline void write_frags512(const ushort_t* __restrict__ XN,
                                      ushort_t* __restrict__ dst, int tid){
  int lane = tid & 63, t8 = tid >> 6;
  int quad = (lane >> 4) & 3, l16 = lane & 15;
  int kk = t8 >> 1, rh = (t8 & 1)*2;
#pragma unroll
  for (int i = 0; i < 2; i++){
    int rt = rh + i;
    uint4 v = *(const uint4*)&XN[(size_t)(rt*16 + l16)*136 + kk*32 + quad*8];
    *(uint4*)(dst + (size_t)((kk*4 + rt)*64 + lane)*8) = v;
  }
}

// LN a 32-elem row-quarter into XN (256-thread layout)
__device__ inline void ln_to_XN(ushort_t* __restrict__ XN, int row, int lq,
                                const float* xr, float mu, float rstd,
                                const float* __restrict__ ln_s,
                                const float* __restrict__ ln_b, int ld){
  uint_t o[16];
#pragma unroll
  for (int k2 = 0; k2 < 16; k2++){
    int c = lq*32 + 2*k2;
    float a = (xr[2*k2]   - mu)*rstd*ln_s[ld*128 + c]     + ln_b[ld*128 + c];
    float b = (xr[2*k2+1] - mu)*rstd*ln_s[ld*128 + c + 1] + ln_b[ld*128 + c + 1];
    o[k2] = cvt_pk_bf16(a, b);
  }
  uint4* dst = (uint4*)&XN[(size_t)row*136 + lq*32];
#pragma unroll
  for (int q = 0; q < 4; q++) dst[q] = make_uint4(o[q*4], o[q*4+1], o[q*4+2], o[q*4+3]);
}

// LN a 16-elem row-eighth into XN (512-thread layout)
__device__ inline void ln_to_XN16(ushort_t* __restrict__ XN, int row, int lq,
                                  const float* xr, float mu, float rstd,
                                  const float* __restrict__ ln_s,
                                  const float* __restrict__ ln_b, int ld){
  uint_t o[8];
#pragma unroll
  for (int k2 = 0; k2 < 8; k2++){
    int c = lq*16 + 2*k2;
    float a = (xr[2*k2]   - mu)*rstd*ln_s[ld*128 + c]     + ln_b[ld*128 + c];
    float b = (xr[2*k2+1] - mu)*rstd*ln_s[ld*128 + c + 1] + ln_b[ld*128 + c + 1];
    o[k2] = cvt_pk_bf16(a, b);
  }
  uint4* dst = (uint4*)&XN[(size_t)row*136 + lq*16];
  dst[0] = make_uint4(o[0], o[1], o[2], o[3]);
  dst[1] = make_uint4(o[4], o[5], o[6], o[7]);
}

// ---------------------------------------------------------------------------
// stage0: xn = LN(Xbuf; layer 0, both dirs) -> xnf fragment files.
// LDS = XN only (17.4 KB) -> high occupancy.
// ---------------------------------------------------------------------------
__global__ __launch_bounds__(256) void stage0_kernel(
    int lnlyr, const ushort_t* __restrict__ Xbuf,
    const float* __restrict__ ln_s, const float* __restrict__ ln_b,
    ushort_t* __restrict__ xnfL, ushort_t* __restrict__ xnfR)
{
  __shared__ __align__(16) ushort_t XN[64*136];    // 17408 B

  const int tid = threadIdx.x;
  const int bj = blockIdx.x;
  const int b = bj / 127, j = bj - b*127;
  const int row = tid >> 2, lq = tid & 3;

  float xr[32];
  {
    const uint4* p = (const uint4*)(Xbuf + ((size_t)(b*64 + row)*N2 + j)*128 + lq*32);
    unpack8(p[0], xr); unpack8(p[1], xr+8); unpack8(p[2], xr+16); unpack8(p[3], xr+24);
  }
  float mu, rstd;
  rowstats(xr, mu, rstd);

  ln_to_XN(XN, row, lq, xr, mu, rstd, ln_s, ln_b, lnlyr*2 + 0);
  __syncthreads();
  write_frags(XN, xnfL + (size_t)bj*8192, tid);
  __syncthreads();
  ln_to_XN(XN, row, lq, xr, mu, rstd, ln_s, ln_b, lnlyr*2 + 1);
  __syncthreads();
  write_frags(XN, xnfR + (size_t)bj*8192, tid);
}

// ---------------------------------------------------------------------------
// stage12 (modes 1,2; 2032 blocks = (b,j), 512 threads / 8 waves).
// mode 1: X' = [hnL@wocL+bocL+LN(X;wl,L)] + shift_m[...R]; X'->Xbuf (in place,
//         own j-slice only); then LN(X'; lnlyr both dirs) -> xnf frags.
// mode 2: like mode 1 but stops after writing X' (the head input).
// 8 waves: wave w8 owns ONE 16-col group (ctg = w8) -> 8 MFMAs/wave (was 16)
// and half the epilogue per wave; LN rows get 8 threads/row.  XNh staging
// kept COALESCED (R10's direct-gather variant regressed).
// ---------------------------------------------------------------------------
__global__ __launch_bounds__(512, 1) void stage12_kernel(
    int mode, int woclyr, int lnlyr,
    ushort_t* __restrict__ Xbuf,
    const ushort_t* __restrict__ hnL, const ushort_t* __restrict__ hnR,
    const ushort_t* __restrict__ wocp, const float* __restrict__ b_oc,
    const float* __restrict__ ln_s, const float* __restrict__ ln_b,
    ushort_t* __restrict__ xnfL, ushort_t* __restrict__ xnfR)
{
  __shared__ __align__(16) float Xout[64*132];     // 33792 B
  __shared__ __align__(16) ushort_t XN[64*136];    // 17408 B
  __shared__ __align__(16) ushort_t XNh[64*72];    //  9216 B   (total 60416)

  const int tid = threadIdx.x;
  const int bj = blockIdx.x;
  const int b = bj / 127, j = bj - b*127;
  const int w8 = tid >> 6;                       // wave: 16-col group
  const int lane = tid & 63, quad = (lane >> 4) & 3, l16 = lane & 15;
  const int row = tid >> 3, lq = tid & 7;        // 8 threads/row, 16 cols each

  // this thread's X row-eighth (bf16 -> fp32 regs)
  float xr[16];
  {
    const uint4* p = (const uint4*)(Xbuf + ((size_t)(b*64 + row)*N2 + j)*128 + lq*16);
    unpack8(p[0], xr); unpack8(p[1], xr+8);
  }
  float mu, rstd;
  rowstats16(xr, mu, rstd);

  // ---- woc epilogues for both directions, combined with m-shift ----
#pragma unroll 1
  for (int s = 0; s < 2; s++){
    const int ld = woclyr*2 + s;
    ln_to_XN16(XN, row, lq, xr, mu, rstd, ln_s, ln_b, ld);   // residual xn
    {
      const ushort_t* hp = s ? hnR : hnL;
      const uint4* p = (const uint4*)(hp + ((size_t)(b*64 + row)*N2 + j)*64 + lq*8);
      *(uint4*)&XNh[(size_t)row*72 + lq*8] = p[0];
    }
    __syncthreads();
    s8bf bw[2];
#pragma unroll
    for (int kk = 0; kk < 2; kk++)
      bw[kk] = *(const s8bf*)(wocp + (size_t)ld*8192 + (size_t)(((kk*8 + w8)*64 + lane)*8));
    f32x4 a2[4];
#pragma unroll
    for (int rt = 0; rt < 4; rt++) a2[rt] = zero4();
#pragma unroll
    for (int kk = 0; kk < 2; kk++)
#pragma unroll
      for (int rt = 0; rt < 4; rt++){
        s8bf a = *(const s8bf*)&XNh[(size_t)(rt*16 + l16)*72 + kk*32 + quad*8];
        a2[rt] = __builtin_amdgcn_mfma_f32_16x16x32_bf16(a, bw[kk], a2[rt], 0, 0, 0);
      }
    const float bv = b_oc[ld*128 + w8*16 + l16];
    const int col = w8*16 + l16;
#pragma unroll
    for (int rt = 0; rt < 4; rt++)
#pragma unroll
      for (int r = 0; r < 4; r++){
        int rr = rt*16 + quad*4 + r;
        float v = a2[rt][r] + bv + bf2f(XN[(size_t)rr*136 + col]);
        if (s == 0) Xout[(size_t)rr*132 + col] = v;
        else if (rr < 63) Xout[(size_t)(rr + 1)*132 + col] += v;  // m-shift; row 0 = left only
      }
    __syncthreads();
  }

  // ---- write combined X back to Xbuf (own j-slice; reads all done) ----
  float xo[16];
#pragma unroll
  for (int k = 0; k < 16; k++) xo[k] = Xout[(size_t)row*132 + lq*16 + k];
  {
    uint_t o[8];
#pragma unroll
    for (int k = 0; k < 8; k++) o[k] = cvt_pk_bf16(xo[2*k], xo[2*k + 1]);
    uint4* dst = (uint4*)(Xbuf + ((size_t)(b*64 + row)*N2 + j)*128 + lq*16);
    dst[0] = make_uint4(o[0], o[1], o[2], o[3]);
    dst[1] = make_uint4(o[4], o[5], o[6], o[7]);
  }
  if (mode == 2) return;

  // ---- LN for the next layer -> fragment files ----
  float mu2, rstd2;
  rowstats16(xo, mu2, rstd2);
  ln_to_XN16(XN, row, lq, xo, mu2, rstd2, ln_s, ln_b, lnlyr*2 + 0);
  __syncthreads();
  write_frags512(XN, xnfL + (size_t)bj*8192, tid);
  __syncthreads();
  ln_to_XN16(XN, row, lq, xo, mu2, rstd2, ln_s, ln_b, lnlyr*2 + 1);
  __syncthreads();
  write_frags512(XN, xnfR + (size_t)bj*8192, tid);
}

// ---------------------------------------------------------------------------
// Diagonal LSTM recurrence, row-split 4 ways: 128 blocks = (d, b, g) with
// row group g owning rows 16g..16g+15.  256 threads / 4 waves; wave w owns
// h-col group w (16 cols x 4 gates).  Cross-group coupling is only the
// one-row hprev shift, handled by a stamped mailbox in d_out scratch:
//   word[col] = (stamp16 << 16) | h_bf16,  stamp = layer*127 + t + 1.
// Producer lanes (quad==3, r==3 hold row 15) fire agent-scope stores from
// registers during the gate phase -- no vmcnt drain, no ordering fence
// (stamp and data share the word, u32 stores are atomic).  Consumer polls
// its 64 words (load issued at loop top, checked after zxa -> MALL latency
// hidden).  Producers never wait on consumers -> no deadlock.
// LDS A double-buffered -> ONE barrier per step.  (Proven 162us/dispatch
// structure.)
// ---------------------------------------------------------------------------
__global__ __launch_bounds__(256, 1) void diag_kernel(
    const ushort_t* __restrict__ xnfL, const ushort_t* __restrict__ xnfR,
    ushort_t* __restrict__ hnL, ushort_t* __restrict__ hnR,
    const ushort_t* __restrict__ zWp, const ushort_t* __restrict__ wisp,
    const float* __restrict__ zbias, const float* __restrict__ h0, int layer,
    uint_t* __restrict__ mb)
{
  __shared__ ushort_t A[2][16][136];  // [buf][row][hprev(0:64)|h(64:128)], +8 pad

  const int tid = threadIdx.x;
  const int g = blockIdx.x & 3;           // row group
  const int b = (blockIdx.x >> 2) & 15;
  const int d = blockIdx.x >> 6;
  const int ld = layer*2 + d;
  const ushort_t* xnf = d ? xnfR : xnfL;
  ushort_t* hp = d ? hnR : hnL;

  const int w = tid >> 6;             // wave = col group (16 cols per gate)
  const int lane = tid & 63;
  const int quad = lane >> 4;
  const int l16 = lane & 15;
  const int cg = w*16 + l16;

  // B fragments: all 4 gates of this wave's col group, wis + wss
  s8bf bss[4][4], bis[4][4];
#pragma unroll
  for (int kk = 0; kk < 4; kk++)
#pragma unroll
    for (int ct = 0; ct < 4; ct++){
      size_t fo = (size_t)(((kk*16 + (w + 4*ct))*64 + lane)*8);
      bss[kk][ct] = *(const s8bf*)(zWp  + (size_t)ld*32768 + fo);
      bis[kk][ct] = *(const s8bf*)(wisp + (size_t)ld*32768 + fo);
    }
  float zb[4];
#pragma unroll
  for (int ct = 0; ct < 4; ct++) zb[ct] = zbias[ld*256 + ct*64 + cg];

  float c_reg[4] = {0.f, 0.f, 0.f, 0.f};

  { // init both A buffers: h carry = h0 broadcast; hprev = h0 (global row 0 -> 0)
    int r2 = tid >> 4, q8 = tid & 15;
    const float* h0p = h0 + ld*64;
#pragma unroll
    for (int k = 0; k < 8; k++){
      int c = q8*8 + k;
      ushort_t hb = f2bf(h0p[c & 63]);
      ushort_t v;
      if (c < 64) v = (g == 0 && r2 == 0) ? (ushort_t)0 : hb;
      else        v = hb;
      A[0][r2][c] = v;
      A[1][r2][c] = v;
    }
  }

  // xf = xn(0) fragments (this group's 16-row tile); zxa(0); prefetch xn(1)
  const int stp8 = d ? -8192 : 8192;
  const ushort_t* xbase = xnf + ((size_t)b*127 + (d ? 126 : 0))*8192;
  uint4 xf[4];
#pragma unroll
  for (int kk = 0; kk < 4; kk++)
    xf[kk] = *(const uint4*)(xbase + (size_t)((kk*4 + g)*64 + lane)*8);

  f32x4 acc[4];
#pragma unroll
  for (int ct = 0; ct < 4; ct++) acc[ct] = splat4(zb[ct]);
#pragma unroll
  for (int kk = 0; kk < 4; kk++){
    s8bf a = *(const s8bf*)&xf[kk];
#pragma unroll
    for (int ct = 0; ct < 4; ct++)
      acc[ct] = __builtin_amdgcn_mfma_f32_16x16x32_bf16(a, bis[kk][ct], acc[ct], 0, 0, 0);
  }
  const ushort_t* pfp = xbase + stp8;   // next prefetch tile (t=1)
#pragma unroll
  for (int kk = 0; kk < 4; kk++)
    xf[kk] = *(const uint4*)(pfp + (size_t)((kk*4 + g)*64 + lane)*8);
  pfp += stp8;

  // running hn store pointer (lane base row = g*16 + quad*4, col cg)
  const int dj64 = d ? -64 : 64;
  ushort_t* hlane = hp + ((size_t)(b*64 + g*16 + quad*4)*N2 + (d ? 126 : 0))*64 + cg;

  // mailbox plumbing: link g = boundary below group g (rows 16g+15 / 16g+16)
  const int bd = b*2 + d;
  uint_t* mbOut = mb + ((size_t)(bd*3 + g)*127)*64;                 // g<3
  const uint_t* mbIn = mb + ((size_t)(bd*3 + (g > 0 ? g - 1 : 0))*127)*64;
  const uint_t stampBase = (uint_t)layer * 127u;
  const bool isProd = (g < 3);
  const bool isCons = (g > 0) && (w == 1);   // full wave: 1 col per lane

  __syncthreads();  // A init visible

#pragma unroll 1
  for (int t = 0; t < 127; t++){
    const int pr = t & 1, pn = pr ^ 1;
    const uint_t stamp = stampBase + (uint_t)t + 1u;
    const bool doFetch = isCons && (t < 126);

    // early poll: issued now, first checked after zxa (MALL latency hidden)
    uint_t pv = 0;
    if (doFetch)
      pv = __hip_atomic_load(mbIn + (size_t)t*64 + lane,
                             __ATOMIC_RELAXED, __HIP_MEMORY_SCOPE_AGENT);

    // ---- phase A: acc += [hprev|h] @ wss ----
#pragma unroll
    for (int kk = 0; kk < 4; kk++){
      s8bf af = *(const s8bf*)&A[pr][l16][kk*32 + quad*8];
#pragma unroll
      for (int ct = 0; ct < 4; ct++)
        acc[ct] = __builtin_amdgcn_mfma_f32_16x16x32_bf16(af, bss[kk][ct], acc[ct], 0, 0, 0);
    }

    // ---- phase B: gates (VALU) + fire-and-forget boundary publish ----
#pragma unroll
    for (int r = 0; r < 4; r++){
      float fg = sigm(acc[0][r]);
      float ig = sigm(acc[1][r]);
      float og = sigm(acc[2][r]);
      float gg = tanhf_(acc[3][r]);
      float cn = fg*c_reg[r] + ig*gg;
      c_reg[r] = cn;
      float hn = og * tanhf_(cn);
      int rr = quad*4 + r;
      ushort_t hb = f2bf(hn);
      A[pn][rr][64 + cg] = hb;
      if (rr < 15) A[pn][rr + 1][cg] = hb;
      hlane[(size_t)r*8128] = hb;
      if (r == 3 && isProd && quad == 3 && t < 126)   // row 15 -> mailbox
        __hip_atomic_store(mbOut + (size_t)t*64 + cg,
                           (stamp << 16) | (uint_t)hb,
                           __ATOMIC_RELAXED, __HIP_MEMORY_SCOPE_AGENT);
    }
    hlane += dj64;

    // ---- phase B: zxa(t+1) = xn(t+1)@wis + zbias ----
    if (t < 126){
#pragma unroll
      for (int ct = 0; ct < 4; ct++) acc[ct] = splat4(zb[ct]);
#pragma unroll
      for (int kk = 0; kk < 4; kk++){
        s8bf a = *(const s8bf*)&xf[kk];
#pragma unroll
        for (int ct = 0; ct < 4; ct++)
          acc[ct] = __builtin_amdgcn_mfma_f32_16x16x32_bf16(a, bis[kk][ct], acc[ct], 0, 0, 0);
      }
      if (t < 125){
#pragma unroll
        for (int kk = 0; kk < 4; kk++)
          xf[kk] = *(const uint4*)(pfp + (size_t)((kk*4 + g)*64 + lane)*8);
        pfp += stp8;
      }
    }

    // ---- consumer: check stamped words; spin only while lead establishes
    if (doFetch){
      while (!__all((pv >> 16) == stamp))
        pv = __hip_atomic_load(mbIn + (size_t)t*64 + lane,
                               __ATOMIC_RELAXED, __HIP_MEMORY_SCOPE_AGENT);
      A[pn][0][lane] = (ushort_t)(pv & 0xffffu);   // neighbor h(t) -> hprev
    }

    __syncthreads(); // new h/hprev (buffer pn) visible for next phase A
  }
}

// ---------------------------------------------------------------------------
// Head: unskew + (128->32)->(32->32)->(32->256), fp32 vector math.
// L1 k-loop chunked 4x32 so the weight array is 32 floats (was 128 VGPRs).
// ---------------------------------------------------------------------------
__global__ __launch_bounds__(256) void head_kernel(
    const ushort_t* __restrict__ xfin,
    const float* __restrict__ w1T, const float* __restrict__ b1,
    const float* __restrict__ w2T, const float* __restrict__ b2,
    const float* __restrict__ whT, const float* __restrict__ bh,
    float* __restrict__ out)
{
  __shared__ float xf[64][132];
  __shared__ float v1[64][36];
  __shared__ float v2[64][36];
  int tid = threadIdx.x;
  int b = blockIdx.x >> 6, i = blockIdx.x & 63;
  {
    int jj = tid >> 2, q = tid & 3;
    size_t base = ((size_t)(b*64 + i)*N2 + (i + jj))*128 + q*32;  // unskew
    const uint4* pL = (const uint4*)(xfin + base);
    float x[32];
    unpack8(pL[0], x); unpack8(pL[1], x+8); unpack8(pL[2], x+16); unpack8(pL[3], x+24);
#pragma unroll
    for (int k = 0; k < 32; k++) xf[jj][q*32 + k] = x[k];
  }
  __syncthreads();
  {
    int c1 = tid & 31, jg = tid >> 5;
    float accv[8];
#pragma unroll
    for (int q = 0; q < 8; q++) accv[q] = b1[c1];
#pragma unroll 1
    for (int kc = 0; kc < 4; kc++){
      float wr[32];
      const float4* wp = (const float4*)(w1T + c1*128 + kc*32);
#pragma unroll
      for (int kk = 0; kk < 8; kk++) ((float4*)wr)[kk] = wp[kk];
#pragma unroll
      for (int jj2 = 0; jj2 < 8; jj2++){
        int jr = jg*8 + jj2;
        float a0=0.f,a1=0.f,a2=0.f,a3=0.f;
#pragma unroll
        for (int kk = 0; kk < 8; kk++){
          float4 xv = *(const float4*)&xf[jr][kc*32 + kk*4];
          a0 += xv.x*wr[kk*4]; a1 += xv.y*wr[kk*4+1]; a2 += xv.z*wr[kk*4+2]; a3 += xv.w*wr[kk*4+3];
        }
        accv[jj2] += (a0+a1)+(a2+a3);
      }
    }
#pragma unroll
    for (int jj2 = 0; jj2 < 8; jj2++) v1[jg*8 + jj2][c1] = accv[jj2];
  }
  __syncthreads();
  {
    int c2 = tid & 31, jg = tid >> 5;
    float wr[32];
    const float4* wp = (const float4*)(w2T + c2*32);
#pragma unroll
    for (int kk = 0; kk < 8; kk++) ((float4*)wr)[kk] = wp[kk];
#pragma unroll 1
    for (int jj2 = 0; jj2 < 8; jj2++){
      int jr = jg*8 + jj2;
      float a0=0.f,a1=0.f,a2=0.f,a3=0.f;
#pragma unroll
      for (int kk = 0; kk < 8; kk++){
        float4 xv = *(const float4*)&v1[jr][kk*4];
        a0 += xv.x*wr[kk*4]; a1 += xv.y*wr[kk*4+1]; a2 += xv.z*wr[kk*4+2]; a3 += xv.w*wr[kk*4+3];
      }
      v2[jr][c2] = b2[c2] + (a0+a1)+(a2+a3);
    }
  }
  __syncthreads();
  {
    int o = tid;
    float wr[32];
    const float4* wp = (const float4*)(whT + o*32);
#pragma unroll
    for (int kk = 0; kk < 8; kk++) ((float4*)wr)[kk] = wp[kk];
    float bo = bh[o];
#pragma unroll 1
    for (int jr = 0; jr < 64; jr++){
      float a0=0.f,a1=0.f,a2=0.f,a3=0.f;
#pragma unroll
      for (int kk = 0; kk < 8; kk++){
        float4 xv = *(const float4*)&v2[jr][kk*4];
        a0 += xv.x*wr[kk*4]; a1 += xv.y*wr[kk*4+1]; a2 += xv.z*wr[kk*4+2]; a3 += xv.w*wr[kk*4+3];
      }
      out[(((size_t)b*64 + i)*64 + jr)*256 + o] = bo + (a0+a1)+(a2+a3);
    }
  }
}

// ---------------------------------------------------------------------------
extern "C" void kernel_launch(void* const* d_in, const int* in_sizes, int n_in,
                              void* d_out, int out_size, void* d_ws, size_t ws_size,
                              hipStream_t stream)
{
  const float* im   = (const float*)d_in[0];
  const float* ck   = (const float*)d_in[1];
  const float* cb   = (const float*)d_in[2];
  const float* ln_s = (const float*)d_in[3];
  const float* ln_b = (const float*)d_in[4];
  const float* w_is = (const float*)d_in[5];
  const float* b_is = (const float*)d_in[6];
  const float* w_ss = (const float*)d_in[7];
  const float* b_ss = (const float*)d_in[8];
  const float* w_oc = (const float*)d_in[9];
  const float* b_oc = (const float*)d_in[10];
  const float* h0   = (const float*)d_in[11];
  const float* w1   = (const float*)d_in[12];
  const float* b1   = (const float*)d_in[13];
  const float* w2   = (const float*)d_in[14];
  const float* b2   = (const float*)d_in[15];
  const float* wh   = (const float*)d_in[16];
  const float* bh   = (const float*)d_in[17];

  // Workspace layout: within Round-1's proven footprint (mailbox lives in
  // d_out, which is dead scratch until head_kernel writes it).
  ushort_t* Xbuf = (ushort_t*)d_ws;        // X0 -> X1 (aliased) -> xfin
  ushort_t* xnfL = Xbuf + ACT;             // xn fragment files (per layer, overwritten)
  ushort_t* xnfR = xnfL + ACT;
  ushort_t* hnL  = xnfR + ACT;
  ushort_t* hnR  = hnL + HNE;
  ushort_t* zWp  = hnR + HNE;              // wss frags  (131072 el)
  ushort_t* wisp = zWp + 131072;           // wis frags  (131072 el)
  ushort_t* wocp = wisp + 131072;          // woc frags  (32768 el)
  float* zbias = (float*)(wocp + 32768);
  float* w1T   = zbias + 1024;
  float* w2T   = w1T + 4096;
  float* whT   = w2T + 1024;
  float* kw    = whT + 8192;
  uint_t* mb   = (uint_t*)d_out;           // stamped handoff mailbox (3.1 MB)

  pack_kernel<<<4268, 256, 0, stream>>>(w_is, w_ss, b_is, b_ss, w_oc, w1, w2, wh, ck,
                                        zWp, wisp, wocp, zbias, w1T, w2T, whT, kw, mb);
  conv_kernel<<<1024, 256, 0, stream>>>(im, cb, kw, Xbuf);
  stage0_kernel<<<2032, 256, 0, stream>>>(0, Xbuf, ln_s, ln_b, xnfL, xnfR);
  diag_kernel<<<128, 256, 0, stream>>>(xnfL, xnfR, hnL, hnR, zWp, wisp, zbias, h0, 0, mb);
  stage12_kernel<<<2032, 512, 0, stream>>>(1, 0, 1, Xbuf, hnL, hnR,
                                           wocp, b_oc, ln_s, ln_b, xnfL, xnfR);
  diag_kernel<<<128, 256, 0, stream>>>(xnfL, xnfR, hnL, hnR, zWp, wisp, zbias, h0, 1, mb);
  stage12_kernel<<<2032, 512, 0, stream>>>(2, 1, 0, Xbuf, hnL, hnR,
                                           wocp, b_oc, ln_s, ln_b, xnfL, xnfR);
  head_kernel<<<1024, 256, 0, stream>>>(Xbuf, w1T, b1, w2T, b2, whT, bh, (float*)d_out);
}

// Round 12
// 656.088 us; speedup vs baseline: 1.1468x; 1.0194x over previous
//
#include <hip/hip_runtime.h>

typedef unsigned short ushort_t;
typedef unsigned int uint_t;
typedef __attribute__((ext_vector_type(8))) short s8bf;   // 8 x bf16 MFMA fragment
typedef __attribute__((ext_vector_type(4))) float f32x4;  // MFMA accumulator

#define N2 127
#define ACT ((size_t)16*64*127*128)     // activation elements (bf16)
#define HNE ((size_t)16*64*127*64)      // hn elements (bf16)
#define MBW ((size_t)32*3*127*64)       // mailbox words (u32), lives in d_out

__device__ inline float bf_lo(uint_t v){ return __uint_as_float(v << 16); }
__device__ inline float bf_hi(uint_t v){ return __uint_as_float(v & 0xffff0000u); }
__device__ inline ushort_t f2bf(float f){
  uint_t u = __float_as_uint(f);
  uint_t r = ((u >> 16) & 1u) + 0x7fffu;  // RNE
  return (ushort_t)((u + r) >> 16);
}
// packed RNE f32x2 -> bf16x2 (same rounding as f2bf, 1 instr instead of ~10)
__device__ inline uint_t cvt_pk_bf16(float lo, float hi){
  uint_t r;
  asm("v_cvt_pk_bf16_f32 %0, %1, %2" : "=v"(r) : "v"(lo), "v"(hi));
  return r;
}
__device__ inline float bf2f(ushort_t h){ return __uint_as_float(((uint_t)h) << 16); }
__device__ inline float frcp(float x){ return __builtin_amdgcn_rcpf(x); }
__device__ inline float sigm(float x){ return frcp(1.f + __expf(-x)); }
__device__ inline float tanhf_(float x){
  // 1 - 2/(1+e^{2x}); saturates correctly for |x| large via inf/0, no clamp
  float e = __expf(2.f * x);
  return 1.f - 2.f * frcp(1.f + e);
}
__device__ inline void unpack8(uint4 u, float* x){
  x[0]=bf_lo(u.x); x[1]=bf_hi(u.x); x[2]=bf_lo(u.y); x[3]=bf_hi(u.y);
  x[4]=bf_lo(u.z); x[5]=bf_hi(u.z); x[6]=bf_lo(u.w); x[7]=bf_hi(u.w);
}
__device__ inline f32x4 zero4(){ f32x4 v; v[0]=0.f; v[1]=0.f; v[2]=0.f; v[3]=0.f; return v; }
__device__ inline f32x4 splat4(float s){ f32x4 v; v[0]=s; v[1]=s; v[2]=s; v[3]=s; return v; }

// 4 threads/row, 32 elems each
__device__ inline void rowstats(const float* xr, float& mu, float& rstd){
  float s0=0.f, q0=0.f;
#pragma unroll
  for (int k = 0; k < 32; k++){ s0 += xr[k]; q0 += xr[k]*xr[k]; }
  s0 += __shfl_xor(s0, 1); q0 += __shfl_xor(q0, 1);
  s0 += __shfl_xor(s0, 2); q0 += __shfl_xor(q0, 2);
  mu = s0 * 0.0078125f;
  float var = q0 * 0.0078125f - mu*mu;
  rstd = rsqrtf(var + 1e-6f);
}

// 8 threads/row, 16 elems each
__device__ inline void rowstats16(const float* xr, float& mu, float& rstd){
  float s0=0.f, q0=0.f;
#pragma unroll
  for (int k = 0; k < 16; k++){ s0 += xr[k]; q0 += xr[k]*xr[k]; }
  s0 += __shfl_xor(s0, 1); q0 += __shfl_xor(q0, 1);
  s0 += __shfl_xor(s0, 2); q0 += __shfl_xor(q0, 2);
  s0 += __shfl_xor(s0, 4); q0 += __shfl_xor(q0, 4);
  mu = s0 * 0.0078125f;
  float var = q0 * 0.0078125f - mu*mu;
  rstd = rsqrtf(var + 1e-6f);
}

// ---------------------------------------------------------------------------
// Pack weights into MFMA B-fragment order.
// zWp: wss (K=128: k 0-63 = wss[.,0] (hprev), 64-127 = wss[.,1] (h)), N=256.
// wisp: wis K=128, N=256.  wocp: K=64, N=128.
// Fragment addr: ((kk*NCTG + ctg)*64 + lane)*8 + e, k = kk*32 + quad*8 + e,
// n = ctg*16 + l16.
// Also zeroes the diag handoff mailbox (in d_out scratch, uint4 stores).
// ---------------------------------------------------------------------------
__global__ void pack_kernel(const float* __restrict__ w_is, const float* __restrict__ w_ss,
                            const float* __restrict__ b_is, const float* __restrict__ b_ss,
                            const float* __restrict__ w_oc, const float* __restrict__ w1,
                            const float* __restrict__ w2, const float* __restrict__ wh,
                            const float* __restrict__ ck,
                            ushort_t* __restrict__ zWp, ushort_t* __restrict__ wisp,
                            ushort_t* __restrict__ wocp,
                            float* __restrict__ zbias, float* __restrict__ w1T,
                            float* __restrict__ w2T, float* __restrict__ whT,
                            float* __restrict__ kw, uint_t* __restrict__ mb)
{
  int idx = blockIdx.x * 256 + threadIdx.x;
  if (idx < 131072){                        // zWp (wss): 4 ld x 32768
    int ld = idx >> 15; int r = idx & 32767;
    int e = r & 7, lane = (r >> 3) & 63, ctg = (r >> 9) & 15, kk = r >> 13;
    int k = kk*32 + ((lane >> 4) & 3)*8 + e;
    int n = ctg*16 + (lane & 15);
    float v;
    if (k < 64) v = w_ss[(((size_t)ld*2 + 0)*64 + k)*256 + n];
    else        v = w_ss[(((size_t)ld*2 + 1)*64 + (k-64))*256 + n];
    zWp[idx] = f2bf(v);
  } else if (idx < 262144){                 // wisp: 4 ld x 32768
    int r0 = idx - 131072;
    int ld = r0 >> 15; int r = r0 & 32767;
    int e = r & 7, lane = (r >> 3) & 63, ctg = (r >> 9) & 15, kk = r >> 13;
    int k = kk*32 + ((lane >> 4) & 3)*8 + e;
    int n = ctg*16 + (lane & 15);
    wisp[r0] = f2bf(w_is[((size_t)ld*128 + k)*256 + n]);
  } else if (idx < 294912){                 // wocp: 4 x 8192
    int r0 = idx - 262144;
    int ld = r0 >> 13; int r = r0 & 8191;
    int e = r & 7, lane = (r >> 3) & 63, ctg = (r >> 9) & 7, kk = (r >> 12) & 1;
    int k = kk*32 + ((lane >> 4) & 3)*8 + e;
    int n = ctg*16 + (lane & 15);
    wocp[r0] = f2bf(w_oc[((size_t)ld*64 + k)*128 + n]);
  } else if (idx < 295936){                 // fused z bias
    int r = idx - 294912;
    zbias[r] = b_is[r] + b_ss[r];
  } else if (idx < 300032){                 // w_out1^T (32,128)
    int r = idx - 295936;
    int c = r >> 7, k = r & 127;
    w1T[r] = w1[k*32 + c];
  } else if (idx < 301056){                 // w_out2^T (32,32)
    int r = idx - 300032;
    int c = r >> 5, k = r & 31;
    w2T[r] = w2[k*32 + c];
  } else if (idx < 309248){                 // w_head^T (256,32)
    int r = idx - 301056;
    int o = r >> 5, k = r & 31;
    whT[r] = wh[k*256 + o];
  } else if (idx < 312320){                 // 24 live conv taps x 128 ch
    int r = idx - 309248;
    int tau = r >> 7, ch = r & 127;
    int di, dj;
    if (tau < 21){ di = tau/7 - 3; dj = tau%7 - 3; } else { di = 0; dj = tau - 24; }
    kw[r] = ck[((di+3)*7 + (dj+3))*128 + ch];
  } else if (idx < (int)(312320 + MBW/4)){  // zero the mailbox, 16B per thread
    ((uint4*)mb)[idx - 312320] = make_uint4(0u, 0u, 0u, 0u);
  }
}

// ---------------------------------------------------------------------------
// Masked 7x7 conv on the implicit skewed image. Output bf16 (B,64,127,128).
// One block per (b,i) row: 4 live im rows (mask keeps only di<=0) staged in
// LDS zero-padded, 24 per-channel weights in registers, loop over j.
// ---------------------------------------------------------------------------
__global__ __launch_bounds__(256) void conv_kernel(const float* __restrict__ im,
                const float* __restrict__ cb, const float* __restrict__ kw,
                ushort_t* __restrict__ out)
{
  __shared__ float ims[4][64];   // rows i-3..i, zero-padded for ii<0
  const int tid = threadIdx.x;
  const int b = blockIdx.x >> 6;
  const int i = blockIdx.x & 63;
  {
    int r = tid >> 6, c = tid & 63;
    int ii = i - 3 + r;
    ims[r][c] = (ii >= 0) ? im[(b*64 + ii)*64 + c] : 0.f;
  }
  const int ch = tid & 127;
  const int jh = tid >> 7;       // 0/1: even/odd j
  float kwreg[24];
#pragma unroll
  for (int tau = 0; tau < 24; tau++) kwreg[tau] = kw[tau*128 + ch];
  const float cbv = cb[ch];
  __syncthreads();
  ushort_t* orow = out + ((size_t)(b*64 + i)*N2)*128 + ch;
#pragma unroll 1
  for (int jt = 0; jt < 64; jt++){
    int j = jt*2 + jh;
    if (j >= N2) break;
    int base = j - i;
    float acc = cbv;
#pragma unroll
    for (int tau = 0; tau < 24; tau++){
      int di = (tau < 21) ? (tau/7 - 3) : 0;
      int dj = (tau < 21) ? (tau%7 - 3) : (tau - 24);
      int jx = base + dj - di;
      int r = di + 3;
      if (jx >= 0 && jx < 64)
        acc += ims[r][jx] * kwreg[tau];
    }
    orow[(size_t)j*128] = f2bf(acc);
  }
}

// write_frags (512-thread): 8 wave-groups, 2 frag rows each
__device__ inline void write_frags512(const ushort_t* __restrict__ XN,
                                      ushort_t* __restrict__ dst, int tid){
  int lane = tid & 63, t8 = tid >> 6;
  int quad = (lane >> 4) & 3, l16 = lane & 15;
  int kk = t8 >> 1, rh = (t8 & 1)*2;
#pragma unroll
  for (int i = 0; i < 2; i++){
    int rt = rh + i;
    uint4 v = *(const uint4*)&XN[(size_t)(rt*16 + l16)*136 + kk*32 + quad*8];
    *(uint4*)(dst + (size_t)((kk*4 + rt)*64 + lane)*8) = v;
  }
}

// LN a 16-elem row-eighth into XN (512-thread layout)
__device__ inline void ln_to_XN16(ushort_t* __restrict__ XN, int row, int lq,
                                  const float* xr, float mu, float rstd,
                                  const float* __restrict__ ln_s,
                                  const float* __restrict__ ln_b, int ld){
  uint_t o[8];
#pragma unroll
  for (int k2 = 0; k2 < 8; k2++){
    int c = lq*16 + 2*k2;
    float a = (xr[2*k2]   - mu)*rstd*ln_s[ld*128 + c]     + ln_b[ld*128 + c];
    float b = (xr[2*k2+1] - mu)*rstd*ln_s[ld*128 + c + 1] + ln_b[ld*128 + c + 1];
    o[k2] = cvt_pk_bf16(a, b);
  }
  uint4* dst = (uint4*)&XN[(size_t)row*136 + lq*16];
  dst[0] = make_uint4(o[0], o[1], o[2], o[3]);
  dst[1] = make_uint4(o[4], o[5], o[6], o[7]);
}

// ---------------------------------------------------------------------------
// stage0 (512 threads): xn = LN(Xbuf; layer 0, both dirs) -> xnf frag files.
// LDS = XN only (17.4 KB); 8 threads/row.
// ---------------------------------------------------------------------------
__global__ __launch_bounds__(512) void stage0_kernel(
    int lnlyr, const ushort_t* __restrict__ Xbuf,
    const float* __restrict__ ln_s, const float* __restrict__ ln_b,
    ushort_t* __restrict__ xnfL, ushort_t* __restrict__ xnfR)
{
  __shared__ __align__(16) ushort_t XN[64*136];    // 17408 B

  const int tid = threadIdx.x;
  const int bj = blockIdx.x;
  const int b = bj / 127, j = bj - b*127;
  const int row = tid >> 3, lq = tid & 7;

  float xr[16];
  {
    const uint4* p = (const uint4*)(Xbuf + ((size_t)(b*64 + row)*N2 + j)*128 + lq*16);
    unpack8(p[0], xr); unpack8(p[1], xr+8);
  }
  float mu, rstd;
  rowstats16(xr, mu, rstd);

  ln_to_XN16(XN, row, lq, xr, mu, rstd, ln_s, ln_b, lnlyr*2 + 0);
  __syncthreads();
  write_frags512(XN, xnfL + (size_t)bj*8192, tid);
  __syncthreads();
  ln_to_XN16(XN, row, lq, xr, mu, rstd, ln_s, ln_b, lnlyr*2 + 1);
  __syncthreads();
  write_frags512(XN, xnfR + (size_t)bj*8192, tid);
}

// ---------------------------------------------------------------------------
// stage12 (modes 1,2; 2032 blocks = (b,j), 512 threads / 8 waves).
// mode 1: X' = [hnL@wocL+bocL+LN(X;wl,L)] + shift_m[...R]; X'->Xbuf (in place,
//         own j-slice only); then LN(X'; lnlyr both dirs) -> xnf frags.
// mode 2: like mode 1 but stops after writing X' (the head input).
// 8 waves: wave w8 owns ONE 16-col group; LN rows get 8 threads/row.
// XNh staging kept COALESCED (direct-gather variant regressed).
// ---------------------------------------------------------------------------
__global__ __launch_bounds__(512, 1) void stage12_kernel(
    int mode, int woclyr, int lnlyr,
    ushort_t* __restrict__ Xbuf,
    const ushort_t* __restrict__ hnL, const ushort_t* __restrict__ hnR,
    const ushort_t* __restrict__ wocp, const float* __restrict__ b_oc,
    const float* __restrict__ ln_s, const float* __restrict__ ln_b,
    ushort_t* __restrict__ xnfL, ushort_t* __restrict__ xnfR)
{
  __shared__ __align__(16) float Xout[64*132];     // 33792 B
  __shared__ __align__(16) ushort_t XN[64*136];    // 17408 B
  __shared__ __align__(16) ushort_t XNh[64*72];    //  9216 B   (total 60416)

  const int tid = threadIdx.x;
  const int bj = blockIdx.x;
  const int b = bj / 127, j = bj - b*127;
  const int w8 = tid >> 6;                       // wave: 16-col group
  const int lane = tid & 63, quad = (lane >> 4) & 3, l16 = lane & 15;
  const int row = tid >> 3, lq = tid & 7;        // 8 threads/row, 16 cols each

  // this thread's X row-eighth (bf16 -> fp32 regs)
  float xr[16];
  {
    const uint4* p = (const uint4*)(Xbuf + ((size_t)(b*64 + row)*N2 + j)*128 + lq*16);
    unpack8(p[0], xr); unpack8(p[1], xr+8);
  }
  float mu, rstd;
  rowstats16(xr, mu, rstd);

  // ---- woc epilogues for both directions, combined with m-shift ----
#pragma unroll 1
  for (int s = 0; s < 2; s++){
    const int ld = woclyr*2 + s;
    ln_to_XN16(XN, row, lq, xr, mu, rstd, ln_s, ln_b, ld);   // residual xn
    {
      const ushort_t* hp = s ? hnR : hnL;
      const uint4* p = (const uint4*)(hp + ((size_t)(b*64 + row)*N2 + j)*64 + lq*8);
      *(uint4*)&XNh[(size_t)row*72 + lq*8] = p[0];
    }
    __syncthreads();
    s8bf bw[2];
#pragma unroll
    for (int kk = 0; kk < 2; kk++)
      bw[kk] = *(const s8bf*)(wocp + (size_t)ld*8192 + (size_t)(((kk*8 + w8)*64 + lane)*8));
    f32x4 a2[4];
#pragma unroll
    for (int rt = 0; rt < 4; rt++) a2[rt] = zero4();
#pragma unroll
    for (int kk = 0; kk < 2; kk++)
#pragma unroll
      for (int rt = 0; rt < 4; rt++){
        s8bf a = *(const s8bf*)&XNh[(size_t)(rt*16 + l16)*72 + kk*32 + quad*8];
        a2[rt] = __builtin_amdgcn_mfma_f32_16x16x32_bf16(a, bw[kk], a2[rt], 0, 0, 0);
      }
    const float bv = b_oc[ld*128 + w8*16 + l16];
    const int col = w8*16 + l16;
#pragma unroll
    for (int rt = 0; rt < 4; rt++)
#pragma unroll
      for (int r = 0; r < 4; r++){
        int rr = rt*16 + quad*4 + r;
        float v = a2[rt][r] + bv + bf2f(XN[(size_t)rr*136 + col]);
        if (s == 0) Xout[(size_t)rr*132 + col] = v;
        else if (rr < 63) Xout[(size_t)(rr + 1)*132 + col] += v;  // m-shift; row 0 = left only
      }
    __syncthreads();
  }

  // ---- write combined X back to Xbuf (own j-slice; reads all done) ----
  float xo[16];
#pragma unroll
  for (int k = 0; k < 16; k++) xo[k] = Xout[(size_t)row*132 + lq*16 + k];
  {
    uint_t o[8];
#pragma unroll
    for (int k = 0; k < 8; k++) o[k] = cvt_pk_bf16(xo[2*k], xo[2*k + 1]);
    uint4* dst = (uint4*)(Xbuf + ((size_t)(b*64 + row)*N2 + j)*128 + lq*16);
    dst[0] = make_uint4(o[0], o[1], o[2], o[3]);
    dst[1] = make_uint4(o[4], o[5], o[6], o[7]);
  }
  if (mode == 2) return;

  // ---- LN for the next layer -> fragment files ----
  float mu2, rstd2;
  rowstats16(xo, mu2, rstd2);
  ln_to_XN16(XN, row, lq, xo, mu2, rstd2, ln_s, ln_b, lnlyr*2 + 0);
  __syncthreads();
  write_frags512(XN, xnfL + (size_t)bj*8192, tid);
  __syncthreads();
  ln_to_XN16(XN, row, lq, xo, mu2, rstd2, ln_s, ln_b, lnlyr*2 + 1);
  __syncthreads();
  write_frags512(XN, xnfR + (size_t)bj*8192, tid);
}

// ---------------------------------------------------------------------------
// Diagonal LSTM recurrence, row-split 4 ways: 128 blocks = (d, b, g) with
// row group g owning rows 16g..16g+15.  256 threads / 4 waves; wave w owns
// h-col group w (16 cols x 4 gates).  Cross-group coupling is only the
// one-row hprev shift, handled by a stamped mailbox in d_out scratch:
//   word[col] = (stamp16 << 16) | h_bf16,  stamp = layer*127 + t + 1.
// Producer lanes (quad==3, r==3 hold row 15) fire agent-scope stores from
// registers during the gate phase -- no vmcnt drain, no ordering fence
// (stamp and data share the word, u32 stores are atomic).  Consumer polls
// its 64 words (load issued at loop top, checked after zxa -> MALL latency
// hidden).  Producers never wait on consumers -> no deadlock.
// LDS A double-buffered -> ONE barrier per step.  (Proven 162us/dispatch
// structure.)
// ---------------------------------------------------------------------------
__global__ __launch_bounds__(256, 1) void diag_kernel(
    const ushort_t* __restrict__ xnfL, const ushort_t* __restrict__ xnfR,
    ushort_t* __restrict__ hnL, ushort_t* __restrict__ hnR,
    const ushort_t* __restrict__ zWp, const ushort_t* __restrict__ wisp,
    const float* __restrict__ zbias, const float* __restrict__ h0, int layer,
    uint_t* __restrict__ mb)
{
  __shared__ ushort_t A[2][16][136];  // [buf][row][hprev(0:64)|h(64:128)], +8 pad

  const int tid = threadIdx.x;
  const int g = blockIdx.x & 3;           // row group
  const int b = (blockIdx.x >> 2) & 15;
  const int d = blockIdx.x >> 6;
  const int ld = layer*2 + d;
  const ushort_t* xnf = d ? xnfR : xnfL;
  ushort_t* hp = d ? hnR : hnL;

  const int w = tid >> 6;             // wave = col group (16 cols per gate)
  const int lane = tid & 63;
  const int quad = lane >> 4;
  const int l16 = lane & 15;
  const int cg = w*16 + l16;

  // B fragments: all 4 gates of this wave's col group, wis + wss
  s8bf bss[4][4], bis[4][4];
#pragma unroll
  for (int kk = 0; kk < 4; kk++)
#pragma unroll
    for (int ct = 0; ct < 4; ct++){
      size_t fo = (size_t)(((kk*16 + (w + 4*ct))*64 + lane)*8);
      bss[kk][ct] = *(const s8bf*)(zWp  + (size_t)ld*32768 + fo);
      bis[kk][ct] = *(const s8bf*)(wisp + (size_t)ld*32768 + fo);
    }
  float zb[4];
#pragma unroll
  for (int ct = 0; ct < 4; ct++) zb[ct] = zbias[ld*256 + ct*64 + cg];

  float c_reg[4] = {0.f, 0.f, 0.f, 0.f};

  { // init both A buffers: h carry = h0 broadcast; hprev = h0 (global row 0 -> 0)
    int r2 = tid >> 4, q8 = tid & 15;
    const float* h0p = h0 + ld*64;
#pragma unroll
    for (int k = 0; k < 8; k++){
      int c = q8*8 + k;
      ushort_t hb = f2bf(h0p[c & 63]);
      ushort_t v;
      if (c < 64) v = (g == 0 && r2 == 0) ? (ushort_t)0 : hb;
      else        v = hb;
      A[0][r2][c] = v;
      A[1][r2][c] = v;
    }
  }

  // xf = xn(0) fragments (this group's 16-row tile); zxa(0); prefetch xn(1)
  const int stp8 = d ? -8192 : 8192;
  const ushort_t* xbase = xnf + ((size_t)b*127 + (d ? 126 : 0))*8192;
  uint4 xf[4];
#pragma unroll
  for (int kk = 0; kk < 4; kk++)
    xf[kk] = *(const uint4*)(xbase + (size_t)((kk*4 + g)*64 + lane)*8);

  f32x4 acc[4];
#pragma unroll
  for (int ct = 0; ct < 4; ct++) acc[ct] = splat4(zb[ct]);
#pragma unroll
  for (int kk = 0; kk < 4; kk++){
    s8bf a = *(const s8bf*)&xf[kk];
#pragma unroll
    for (int ct = 0; ct < 4; ct++)
      acc[ct] = __builtin_amdgcn_mfma_f32_16x16x32_bf16(a, bis[kk][ct], acc[ct], 0, 0, 0);
  }
  const ushort_t* pfp = xbase + stp8;   // next prefetch tile (t=1)
#pragma unroll
  for (int kk = 0; kk < 4; kk++)
    xf[kk] = *(const uint4*)(pfp + (size_t)((kk*4 + g)*64 + lane)*8);
  pfp += stp8;

  // running hn store pointer (lane base row = g*16 + quad*4, col cg)
  const int dj64 = d ? -64 : 64;
  ushort_t* hlane = hp + ((size_t)(b*64 + g*16 + quad*4)*N2 + (d ? 126 : 0))*64 + cg;

  // mailbox plumbing: link g = boundary below group g (rows 16g+15 / 16g+16)
  const int bd = b*2 + d;
  uint_t* mbOut = mb + ((size_t)(bd*3 + g)*127)*64;                 // g<3
  const uint_t* mbIn = mb + ((size_t)(bd*3 + (g > 0 ? g - 1 : 0))*127)*64;
  const uint_t stampBase = (uint_t)layer * 127u;
  const bool isProd = (g < 3);
  const bool isCons = (g > 0) && (w == 1);   // full wave: 1 col per lane

  __syncthreads();  // A init visible

#pragma unroll 1
  for (int t = 0; t < 127; t++){
    const int pr = t & 1, pn = pr ^ 1;
    const uint_t stamp = stampBase + (uint_t)t + 1u;
    const bool doFetch = isCons && (t < 126);

    // early poll: issued now, first checked after zxa (MALL latency hidden)
    uint_t pv = 0;
    if (doFetch)
      pv = __hip_atomic_load(mbIn + (size_t)t*64 + lane,
                             __ATOMIC_RELAXED, __HIP_MEMORY_SCOPE_AGENT);

    // ---- phase A: acc += [hprev|h] @ wss ----
#pragma unroll
    for (int kk = 0; kk < 4; kk++){
      s8bf af = *(const s8bf*)&A[pr][l16][kk*32 + quad*8];
#pragma unroll
      for (int ct = 0; ct < 4; ct++)
        acc[ct] = __builtin_amdgcn_mfma_f32_16x16x32_bf16(af, bss[kk][ct], acc[ct], 0, 0, 0);
    }

    // ---- phase B: gates (VALU) + fire-and-forget boundary publish ----
#pragma unroll
    for (int r = 0; r < 4; r++){
      float fg = sigm(acc[0][r]);
      float ig = sigm(acc[1][r]);
      float og = sigm(acc[2][r]);
      float gg = tanhf_(acc[3][r]);
      float cn = fg*c_reg[r] + ig*gg;
      c_reg[r] = cn;
      float hn = og * tanhf_(cn);
      int rr = quad*4 + r;
      ushort_t hb = f2bf(hn);
      A[pn][rr][64 + cg] = hb;
      if (rr < 15) A[pn][rr + 1][cg] = hb;
      hlane[(size_t)r*8128] = hb;
      if (r == 3 && isProd && quad == 3 && t < 126)   // row 15 -> mailbox
        __hip_atomic_store(mbOut + (size_t)t*64 + cg,
                           (stamp << 16) | (uint_t)hb,
                           __ATOMIC_RELAXED, __HIP_MEMORY_SCOPE_AGENT);
    }
    hlane += dj64;

    // ---- phase B: zxa(t+1) = xn(t+1)@wis + zbias ----
    if (t < 126){
#pragma unroll
      for (int ct = 0; ct < 4; ct++) acc[ct] = splat4(zb[ct]);
#pragma unroll
      for (int kk = 0; kk < 4; kk++){
        s8bf a = *(const s8bf*)&xf[kk];
#pragma unroll
        for (int ct = 0; ct < 4; ct++)
          acc[ct] = __builtin_amdgcn_mfma_f32_16x16x32_bf16(a, bis[kk][ct], acc[ct], 0, 0, 0);
      }
      if (t < 125){
#pragma unroll
        for (int kk = 0; kk < 4; kk++)
          xf[kk] = *(const uint4*)(pfp + (size_t)((kk*4 + g)*64 + lane)*8);
        pfp += stp8;
      }
    }

    // ---- consumer: check stamped words; spin only while lead establishes
    if (doFetch){
      while (!__all((pv >> 16) == stamp))
        pv = __hip_atomic_load(mbIn + (size_t)t*64 + lane,
                               __ATOMIC_RELAXED, __HIP_MEMORY_SCOPE_AGENT);
      A[pn][0][lane] = (ushort_t)(pv & 0xffffu);   // neighbor h(t) -> hprev
    }

    __syncthreads(); // new h/hprev (buffer pn) visible for next phase A
  }
}

// ---------------------------------------------------------------------------
// Head (512 threads): unskew + (128->32)->(32->32)->(32->256), fp32 vector.
// Stage-1/2: 16 row-groups x 4 rows.  Stage-3: jr loop split across 2 halves.
// ---------------------------------------------------------------------------
__global__ __launch_bounds__(512) void head_kernel(
    const ushort_t* __restrict__ xfin,
    const float* __restrict__ w1T, const float* __restrict__ b1,
    const float* __restrict__ w2T, const float* __restrict__ b2,
    const float* __restrict__ whT, const float* __restrict__ bh,
    float* __restrict__ out)
{
  __shared__ float xf[64][132];
  __shared__ float v1[64][36];
  __shared__ float v2[64][36];
  int tid = threadIdx.x;
  int b = blockIdx.x >> 6, i = blockIdx.x & 63;
  {
    int jj = tid >> 3, q = tid & 7;
    size_t base = ((size_t)(b*64 + i)*N2 + (i + jj))*128 + q*16;  // unskew
    const uint4* pL = (const uint4*)(xfin + base);
    float x[16];
    unpack8(pL[0], x); unpack8(pL[1], x+8);
#pragma unroll
    for (int k = 0; k < 16; k++) xf[jj][q*16 + k] = x[k];
  }
  __syncthreads();
  {
    int c1 = tid & 31, jg = tid >> 5;     // 16 groups x 4 rows
    float accv[4];
#pragma unroll
    for (int q = 0; q < 4; q++) accv[q] = b1[c1];
#pragma unroll 1
    for (int kc = 0; kc < 4; kc++){
      float wr[32];
      const float4* wp = (const float4*)(w1T + c1*128 + kc*32);
#pragma unroll
      for (int kk = 0; kk < 8; kk++) ((float4*)wr)[kk] = wp[kk];
#pragma unroll
      for (int jj2 = 0; jj2 < 4; jj2++){
        int jr = jg*4 + jj2;
        float a0=0.f,a1=0.f,a2=0.f,a3=0.f;
#pragma unroll
        for (int kk = 0; kk < 8; kk++){
          float4 xv = *(const float4*)&xf[jr][kc*32 + kk*4];
          a0 += xv.x*wr[kk*4]; a1 += xv.y*wr[kk*4+1]; a2 += xv.z*wr[kk*4+2]; a3 += xv.w*wr[kk*4+3];
        }
        accv[jj2] += (a0+a1)+(a2+a3);
      }
    }
#pragma unroll
    for (int jj2 = 0; jj2 < 4; jj2++) v1[jg*4 + jj2][c1] = accv[jj2];
  }
  __syncthreads();
  {
    int c2 = tid & 31, jg = tid >> 5;     // 16 groups x 4 rows
    float wr[32];
    const float4* wp = (const float4*)(w2T + c2*32);
#pragma unroll
    for (int kk = 0; kk < 8; kk++) ((float4*)wr)[kk] = wp[kk];
#pragma unroll
    for (int jj2 = 0; jj2 < 4; jj2++){
      int jr = jg*4 + jj2;
      float a0=0.f,a1=0.f,a2=0.f,a3=0.f;
#pragma unroll
      for (int kk = 0; kk < 8; kk++){
        float4 xv = *(const float4*)&v1[jr][kk*4];
        a0 += xv.x*wr[kk*4]; a1 += xv.y*wr[kk*4+1]; a2 += xv.z*wr[kk*4+2]; a3 += xv.w*wr[kk*4+3];
      }
      v2[jr][c2] = b2[c2] + (a0+a1)+(a2+a3);
    }
  }
  __syncthreads();
  {
    int o = tid & 255, jh = tid >> 8;     // two halves of the jr range
    float wr[32];
    const float4* wp = (const float4*)(whT + o*32);
#pragma unroll
    for (int kk = 0; kk < 8; kk++) ((float4*)wr)[kk] = wp[kk];
    float bo = bh[o];
#pragma unroll 1
    for (int jr2 = 0; jr2 < 32; jr2++){
      int jr = jh*32 + jr2;
      float a0=0.f,a1=0.f,a2=0.f,a3=0.f;
#pragma unroll
      for (int kk = 0; kk < 8; kk++){
        float4 xv = *(const float4*)&v2[jr][kk*4];
        a0 += xv.x*wr[kk*4]; a1 += xv.y*wr[kk*4+1]; a2 += xv.z*wr[kk*4+2]; a3 += xv.w*wr[kk*4+3];
      }
      out[(((size_t)b*64 + i)*64 + jr)*256 + o] = bo + (a0+a1)+(a2+a3);
    }
  }
}

// ---------------------------------------------------------------------------
extern "C" void kernel_launch(void* const* d_in, const int* in_sizes, int n_in,
                              void* d_out, int out_size, void* d_ws, size_t ws_size,
                              hipStream_t stream)
{
  const float* im   = (const float*)d_in[0];
  const float* ck   = (const float*)d_in[1];
  const float* cb   = (const float*)d_in[2];
  const float* ln_s = (const float*)d_in[3];
  const float* ln_b = (const float*)d_in[4];
  const float* w_is = (const float*)d_in[5];
  const float* b_is = (const float*)d_in[6];
  const float* w_ss = (const float*)d_in[7];
  const float* b_ss = (const float*)d_in[8];
  const float* w_oc = (const float*)d_in[9];
  const float* b_oc = (const float*)d_in[10];
  const float* h0   = (const float*)d_in[11];
  const float* w1   = (const float*)d_in[12];
  const float* b1   = (const float*)d_in[13];
  const float* w2   = (const float*)d_in[14];
  const float* b2   = (const float*)d_in[15];
  const float* wh   = (const float*)d_in[16];
  const float* bh   = (const float*)d_in[17];

  // Workspace layout: within Round-1's proven footprint (mailbox lives in
  // d_out, which is dead scratch until head_kernel writes it).
  ushort_t* Xbuf = (ushort_t*)d_ws;        // X0 -> X1 (aliased) -> xfin
  ushort_t* xnfL = Xbuf + ACT;             // xn fragment files (per layer, overwritten)
  ushort_t* xnfR = xnfL + ACT;
  ushort_t* hnL  = xnfR + ACT;
  ushort_t* hnR  = hnL + HNE;
  ushort_t* zWp  = hnR + HNE;              // wss frags  (131072 el)
  ushort_t* wisp = zWp + 131072;           // wis frags  (131072 el)
  ushort_t* wocp = wisp + 131072;          // woc frags  (32768 el)
  float* zbias = (float*)(wocp + 32768);
  float* w1T   = zbias + 1024;
  float* w2T   = w1T + 4096;
  float* whT   = w2T + 1024;
  float* kw    = whT + 8192;
  uint_t* mb   = (uint_t*)d_out;           // stamped handoff mailbox (3.1 MB)

  pack_kernel<<<1982, 256, 0, stream>>>(w_is, w_ss, b_is, b_ss, w_oc, w1, w2, wh, ck,
                                        zWp, wisp, wocp, zbias, w1T, w2T, whT, kw, mb);
  conv_kernel<<<1024, 256, 0, stream>>>(im, cb, kw, Xbuf);
  stage0_kernel<<<2032, 512, 0, stream>>>(0, Xbuf, ln_s, ln_b, xnfL, xnfR);
  diag_kernel<<<128, 256, 0, stream>>>(xnfL, xnfR, hnL, hnR, zWp, wisp, zbias, h0, 0, mb);
  stage12_kernel<<<2032, 512, 0, stream>>>(1, 0, 1, Xbuf, hnL, hnR,
                                           wocp, b_oc, ln_s, ln_b, xnfL, xnfR);
  diag_kernel<<<128, 256, 0, stream>>>(xnfL, xnfR, hnL, hnR, zWp, wisp, zbias, h0, 1, mb);
  stage12_kernel<<<2032, 512, 0, stream>>>(2, 1, 0, Xbuf, hnL, hnR,
                                           wocp, b_oc, ln_s, ln_b, xnfL, xnfR);
  head_kernel<<<1024, 512, 0, stream>>>(Xbuf, w1T, b1, w2T, b2, whT, bh, (float*)d_out);
}

// Round 13
// 655.415 us; speedup vs baseline: 1.1480x; 1.0010x over previous
//
#include <hip/hip_runtime.h>

typedef unsigned short ushort_t;
typedef unsigned int uint_t;
typedef __attribute__((ext_vector_type(8))) short s8bf;   // 8 x bf16 MFMA fragment
typedef __attribute__((ext_vector_type(4))) float f32x4;  // MFMA accumulator

#define N2 127
#define ACT ((size_t)16*64*127*128)     // activation elements (bf16)
#define HNE ((size_t)16*64*127*64)      // hn elements (bf16)
#define MBW ((size_t)32*3*127*64)       // mailbox words (u32), lives in d_out

__device__ inline float bf_lo(uint_t v){ return __uint_as_float(v << 16); }
__device__ inline float bf_hi(uint_t v){ return __uint_as_float(v & 0xffff0000u); }
__device__ inline ushort_t f2bf(float f){
  uint_t u = __float_as_uint(f);
  uint_t r = ((u >> 16) & 1u) + 0x7fffu;  // RNE
  return (ushort_t)((u + r) >> 16);
}
// packed RNE f32x2 -> bf16x2 (same rounding as f2bf, 1 instr instead of ~10)
__device__ inline uint_t cvt_pk_bf16(float lo, float hi){
  uint_t r;
  asm("v_cvt_pk_bf16_f32 %0, %1, %2" : "=v"(r) : "v"(lo), "v"(hi));
  return r;
}
__device__ inline float bf2f(ushort_t h){ return __uint_as_float(((uint_t)h) << 16); }
__device__ inline float frcp(float x){ return __builtin_amdgcn_rcpf(x); }
__device__ inline float sigm(float x){ return frcp(1.f + __expf(-x)); }
__device__ inline float tanhf_(float x){
  // 1 - 2/(1+e^{2x}); saturates correctly for |x| large via inf/0, no clamp
  float e = __expf(2.f * x);
  return 1.f - 2.f * frcp(1.f + e);
}
__device__ inline void unpack8(uint4 u, float* x){
  x[0]=bf_lo(u.x); x[1]=bf_hi(u.x); x[2]=bf_lo(u.y); x[3]=bf_hi(u.y);
  x[4]=bf_lo(u.z); x[5]=bf_hi(u.z); x[6]=bf_lo(u.w); x[7]=bf_hi(u.w);
}
__device__ inline f32x4 zero4(){ f32x4 v; v[0]=0.f; v[1]=0.f; v[2]=0.f; v[3]=0.f; return v; }
__device__ inline f32x4 splat4(float s){ f32x4 v; v[0]=s; v[1]=s; v[2]=s; v[3]=s; return v; }

// 8 threads/row, 16 elems each
__device__ inline void rowstats16(const float* xr, float& mu, float& rstd){
  float s0=0.f, q0=0.f;
#pragma unroll
  for (int k = 0; k < 16; k++){ s0 += xr[k]; q0 += xr[k]*xr[k]; }
  s0 += __shfl_xor(s0, 1); q0 += __shfl_xor(q0, 1);
  s0 += __shfl_xor(s0, 2); q0 += __shfl_xor(q0, 2);
  s0 += __shfl_xor(s0, 4); q0 += __shfl_xor(q0, 4);
  mu = s0 * 0.0078125f;
  float var = q0 * 0.0078125f - mu*mu;
  rstd = rsqrtf(var + 1e-6f);
}

// ---------------------------------------------------------------------------
// prep_kernel = conv (blocks 0..1023) + pack (blocks 1024..3005), fused:
// conv reads ck directly (compile-time tap map) so it has no dependency on
// the pack half -- the two overlap inside one launch.
//
// conv: masked 7x7 conv on the implicit skewed image -> bf16 (B,64,127,128).
// One block per (b,i) row; 4 live im rows (mask keeps di<=0) in LDS.
//
// pack: MFMA B-fragment packing (zWp/wisp/wocp), fused z bias, transposed
// head weights, and mailbox zeroing (uint4 stores).
// ---------------------------------------------------------------------------
__global__ __launch_bounds__(256) void prep_kernel(
    const float* __restrict__ im, const float* __restrict__ cb,
    const float* __restrict__ ck,
    const float* __restrict__ w_is, const float* __restrict__ w_ss,
    const float* __restrict__ b_is, const float* __restrict__ b_ss,
    const float* __restrict__ w_oc, const float* __restrict__ w1,
    const float* __restrict__ w2, const float* __restrict__ wh,
    ushort_t* __restrict__ out,
    ushort_t* __restrict__ zWp, ushort_t* __restrict__ wisp,
    ushort_t* __restrict__ wocp,
    float* __restrict__ zbias, float* __restrict__ w1T,
    float* __restrict__ w2T, float* __restrict__ whT,
    uint_t* __restrict__ mb)
{
  __shared__ float ims[4][64];   // conv: rows i-3..i, zero-padded for ii<0
  const int tid = threadIdx.x;

  if (blockIdx.x < 1024){
    // ---------------- conv half ----------------
    const int b = blockIdx.x >> 6;
    const int i = blockIdx.x & 63;
    {
      int r = tid >> 6, c = tid & 63;
      int ii = i - 3 + r;
      ims[r][c] = (ii >= 0) ? im[(b*64 + ii)*64 + c] : 0.f;
    }
    const int ch = tid & 127;
    const int jh = tid >> 7;       // 0/1: even/odd j
    float kwreg[24];
#pragma unroll
    for (int tau = 0; tau < 24; tau++){
      int di = (tau < 21) ? (tau/7 - 3) : 0;
      int dj = (tau < 21) ? (tau%7 - 3) : (tau - 24);
      kwreg[tau] = ck[((di+3)*7 + (dj+3))*128 + ch];
    }
    const float cbv = cb[ch];
    __syncthreads();
    ushort_t* orow = out + ((size_t)(b*64 + i)*N2)*128 + ch;
#pragma unroll 1
    for (int jt = 0; jt < 64; jt++){
      int j = jt*2 + jh;
      if (j >= N2) break;
      int base = j - i;
      float acc = cbv;
#pragma unroll
      for (int tau = 0; tau < 24; tau++){
        int di = (tau < 21) ? (tau/7 - 3) : 0;
        int dj = (tau < 21) ? (tau%7 - 3) : (tau - 24);
        int jx = base + dj - di;
        int r = di + 3;
        if (jx >= 0 && jx < 64)
          acc += ims[r][jx] * kwreg[tau];
      }
      orow[(size_t)j*128] = f2bf(acc);
    }
    return;
  }

  // ---------------- pack half ----------------
  int idx = (blockIdx.x - 1024) * 256 + tid;
  if (idx < 131072){                        // zWp (wss): 4 ld x 32768
    int ld = idx >> 15; int r = idx & 32767;
    int e = r & 7, lane = (r >> 3) & 63, ctg = (r >> 9) & 15, kk = r >> 13;
    int k = kk*32 + ((lane >> 4) & 3)*8 + e;
    int n = ctg*16 + (lane & 15);
    float v;
    if (k < 64) v = w_ss[(((size_t)ld*2 + 0)*64 + k)*256 + n];
    else        v = w_ss[(((size_t)ld*2 + 1)*64 + (k-64))*256 + n];
    zWp[idx] = f2bf(v);
  } else if (idx < 262144){                 // wisp: 4 ld x 32768
    int r0 = idx - 131072;
    int ld = r0 >> 15; int r = r0 & 32767;
    int e = r & 7, lane = (r >> 3) & 63, ctg = (r >> 9) & 15, kk = r >> 13;
    int k = kk*32 + ((lane >> 4) & 3)*8 + e;
    int n = ctg*16 + (lane & 15);
    wisp[r0] = f2bf(w_is[((size_t)ld*128 + k)*256 + n]);
  } else if (idx < 294912){                 // wocp: 4 x 8192
    int r0 = idx - 262144;
    int ld = r0 >> 13; int r = r0 & 8191;
    int e = r & 7, lane = (r >> 3) & 63, ctg = (r >> 9) & 7, kk = (r >> 12) & 1;
    int k = kk*32 + ((lane >> 4) & 3)*8 + e;
    int n = ctg*16 + (lane & 15);
    wocp[r0] = f2bf(w_oc[((size_t)ld*64 + k)*128 + n]);
  } else if (idx < 295936){                 // fused z bias
    int r = idx - 294912;
    zbias[r] = b_is[r] + b_ss[r];
  } else if (idx < 300032){                 // w_out1^T (32,128)
    int r = idx - 295936;
    int c = r >> 7, k = r & 127;
    w1T[r] = w1[k*32 + c];
  } else if (idx < 301056){                 // w_out2^T (32,32)
    int r = idx - 300032;
    int c = r >> 5, k = r & 31;
    w2T[r] = w2[k*32 + c];
  } else if (idx < 309248){                 // w_head^T (256,32)
    int r = idx - 301056;
    int o = r >> 5, k = r & 31;
    whT[r] = wh[k*256 + o];
  } else if (idx >= 312320 && idx < (int)(312320 + MBW/4)){  // zero mailbox, 16B/thr
    ((uint4*)mb)[idx - 312320] = make_uint4(0u, 0u, 0u, 0u);
  }
}

// write_frags (512-thread): 8 wave-groups, 2 frag rows each
__device__ inline void write_frags512(const ushort_t* __restrict__ XN,
                                      ushort_t* __restrict__ dst, int tid){
  int lane = tid & 63, t8 = tid >> 6;
  int quad = (lane >> 4) & 3, l16 = lane & 15;
  int kk = t8 >> 1, rh = (t8 & 1)*2;
#pragma unroll
  for (int i = 0; i < 2; i++){
    int rt = rh + i;
    uint4 v = *(const uint4*)&XN[(size_t)(rt*16 + l16)*136 + kk*32 + quad*8];
    *(uint4*)(dst + (size_t)((kk*4 + rt)*64 + lane)*8) = v;
  }
}

// LN a 16-elem row-eighth into XN (512-thread layout)
__device__ inline void ln_to_XN16(ushort_t* __restrict__ XN, int row, int lq,
                                  const float* xr, float mu, float rstd,
                                  const float* __restrict__ ln_s,
                                  const float* __restrict__ ln_b, int ld){
  uint_t o[8];
#pragma unroll
  for (int k2 = 0; k2 < 8; k2++){
    int c = lq*16 + 2*k2;
    float a = (xr[2*k2]   - mu)*rstd*ln_s[ld*128 + c]     + ln_b[ld*128 + c];
    float b = (xr[2*k2+1] - mu)*rstd*ln_s[ld*128 + c + 1] + ln_b[ld*128 + c + 1];
    o[k2] = cvt_pk_bf16(a, b);
  }
  uint4* dst = (uint4*)&XN[(size_t)row*136 + lq*16];
  dst[0] = make_uint4(o[0], o[1], o[2], o[3]);
  dst[1] = make_uint4(o[4], o[5], o[6], o[7]);
}

// ---------------------------------------------------------------------------
// stage0 (512 threads): xn = LN(Xbuf; layer 0, both dirs) -> xnf frag files.
// LDS = XN only (17.4 KB); 8 threads/row.
// ---------------------------------------------------------------------------
__global__ __launch_bounds__(512) void stage0_kernel(
    int lnlyr, const ushort_t* __restrict__ Xbuf,
    const float* __restrict__ ln_s, const float* __restrict__ ln_b,
    ushort_t* __restrict__ xnfL, ushort_t* __restrict__ xnfR)
{
  __shared__ __align__(16) ushort_t XN[64*136];    // 17408 B

  const int tid = threadIdx.x;
  const int bj = blockIdx.x;
  const int b = bj / 127, j = bj - b*127;
  const int row = tid >> 3, lq = tid & 7;

  float xr[16];
  {
    const uint4* p = (const uint4*)(Xbuf + ((size_t)(b*64 + row)*N2 + j)*128 + lq*16);
    unpack8(p[0], xr); unpack8(p[1], xr+8);
  }
  float mu, rstd;
  rowstats16(xr, mu, rstd);

  ln_to_XN16(XN, row, lq, xr, mu, rstd, ln_s, ln_b, lnlyr*2 + 0);
  __syncthreads();
  write_frags512(XN, xnfL + (size_t)bj*8192, tid);
  __syncthreads();
  ln_to_XN16(XN, row, lq, xr, mu, rstd, ln_s, ln_b, lnlyr*2 + 1);
  __syncthreads();
  write_frags512(XN, xnfR + (size_t)bj*8192, tid);
}

// ---------------------------------------------------------------------------
// stage12 (modes 1,2; 2032 blocks = (b,j), 512 threads / 8 waves).
// mode 1: X' = [hnL@wocL+bocL+LN(X;wl,L)] + shift_m[...R]; X'->Xbuf (in place,
//         own j-slice only); then LN(X'; lnlyr both dirs) -> xnf frags.
// mode 2: like mode 1 but stops after writing X' (the head input).
// 8 waves: wave w8 owns ONE 16-col group; LN rows get 8 threads/row.
// XNh staging kept COALESCED (direct-gather variant regressed).
// ---------------------------------------------------------------------------
__global__ __launch_bounds__(512, 1) void stage12_kernel(
    int mode, int woclyr, int lnlyr,
    ushort_t* __restrict__ Xbuf,
    const ushort_t* __restrict__ hnL, const ushort_t* __restrict__ hnR,
    const ushort_t* __restrict__ wocp, const float* __restrict__ b_oc,
    const float* __restrict__ ln_s, const float* __restrict__ ln_b,
    ushort_t* __restrict__ xnfL, ushort_t* __restrict__ xnfR)
{
  __shared__ __align__(16) float Xout[64*132];     // 33792 B
  __shared__ __align__(16) ushort_t XN[64*136];    // 17408 B
  __shared__ __align__(16) ushort_t XNh[64*72];    //  9216 B   (total 60416)

  const int tid = threadIdx.x;
  const int bj = blockIdx.x;
  const int b = bj / 127, j = bj - b*127;
  const int w8 = tid >> 6;                       // wave: 16-col group
  const int lane = tid & 63, quad = (lane >> 4) & 3, l16 = lane & 15;
  const int row = tid >> 3, lq = tid & 7;        // 8 threads/row, 16 cols each

  // this thread's X row-eighth (bf16 -> fp32 regs)
  float xr[16];
  {
    const uint4* p = (const uint4*)(Xbuf + ((size_t)(b*64 + row)*N2 + j)*128 + lq*16);
    unpack8(p[0], xr); unpack8(p[1], xr+8);
  }
  float mu, rstd;
  rowstats16(xr, mu, rstd);

  // ---- woc epilogues for both directions, combined with m-shift ----
#pragma unroll 1
  for (int s = 0; s < 2; s++){
    const int ld = woclyr*2 + s;
    ln_to_XN16(XN, row, lq, xr, mu, rstd, ln_s, ln_b, ld);   // residual xn
    {
      const ushort_t* hp = s ? hnR : hnL;
      const uint4* p = (const uint4*)(hp + ((size_t)(b*64 + row)*N2 + j)*64 + lq*8);
      *(uint4*)&XNh[(size_t)row*72 + lq*8] = p[0];
    }
    __syncthreads();
    s8bf bw[2];
#pragma unroll
    for (int kk = 0; kk < 2; kk++)
      bw[kk] = *(const s8bf*)(wocp + (size_t)ld*8192 + (size_t)(((kk*8 + w8)*64 + lane)*8));
    f32x4 a2[4];
#pragma unroll
    for (int rt = 0; rt < 4; rt++) a2[rt] = zero4();
#pragma unroll
    for (int kk = 0; kk < 2; kk++)
#pragma unroll
      for (int rt = 0; rt < 4; rt++){
        s8bf a = *(const s8bf*)&XNh[(size_t)(rt*16 + l16)*72 + kk*32 + quad*8];
        a2[rt] = __builtin_amdgcn_mfma_f32_16x16x32_bf16(a, bw[kk], a2[rt], 0, 0, 0);
      }
    const float bv = b_oc[ld*128 + w8*16 + l16];
    const int col = w8*16 + l16;
#pragma unroll
    for (int rt = 0; rt < 4; rt++)
#pragma unroll
      for (int r = 0; r < 4; r++){
        int rr = rt*16 + quad*4 + r;
        float v = a2[rt][r] + bv + bf2f(XN[(size_t)rr*136 + col]);
        if (s == 0) Xout[(size_t)rr*132 + col] = v;
        else if (rr < 63) Xout[(size_t)(rr + 1)*132 + col] += v;  // m-shift; row 0 = left only
      }
    __syncthreads();
  }

  // ---- write combined X back to Xbuf (own j-slice; reads all done) ----
  float xo[16];
#pragma unroll
  for (int k = 0; k < 16; k++) xo[k] = Xout[(size_t)row*132 + lq*16 + k];
  {
    uint_t o[8];
#pragma unroll
    for (int k = 0; k < 8; k++) o[k] = cvt_pk_bf16(xo[2*k], xo[2*k + 1]);
    uint4* dst = (uint4*)(Xbuf + ((size_t)(b*64 + row)*N2 + j)*128 + lq*16);
    dst[0] = make_uint4(o[0], o[1], o[2], o[3]);
    dst[1] = make_uint4(o[4], o[5], o[6], o[7]);
  }
  if (mode == 2) return;

  // ---- LN for the next layer -> fragment files ----
  float mu2, rstd2;
  rowstats16(xo, mu2, rstd2);
  ln_to_XN16(XN, row, lq, xo, mu2, rstd2, ln_s, ln_b, lnlyr*2 + 0);
  __syncthreads();
  write_frags512(XN, xnfL + (size_t)bj*8192, tid);
  __syncthreads();
  ln_to_XN16(XN, row, lq, xo, mu2, rstd2, ln_s, ln_b, lnlyr*2 + 1);
  __syncthreads();
  write_frags512(XN, xnfR + (size_t)bj*8192, tid);
}

// ---------------------------------------------------------------------------
// Diagonal LSTM recurrence, row-split 4 ways: 128 blocks = (d, b, g) with
// row group g owning rows 16g..16g+15.  256 threads / 4 waves; wave w owns
// h-col group w (16 cols x 4 gates).  Cross-group coupling is only the
// one-row hprev shift, handled by a stamped mailbox in d_out scratch:
//   word[col] = (stamp16 << 16) | h_bf16,  stamp = layer*127 + t + 1.
// Producer lanes fire agent-scope stores from registers during the gate
// phase -- no fence (stamp+data share the atomic word).  Consumer polls
// (load at loop top, checked after zxa -> MALL latency hidden).  Producers
// never wait on consumers -> no deadlock.  LDS A double-buffered -> ONE
// barrier per step.  CHANGE vs the 161.7us build: the per-step barrier is
// raw lgkmcnt(0)+s_barrier (no vmcnt drain) -- hn/mailbox stores and xf
// prefetch stay in flight across steps; LDS ordering (all the barrier must
// provide) is preserved.  Everything else byte-identical.
// ---------------------------------------------------------------------------
__global__ __launch_bounds__(256, 1) void diag_kernel(
    const ushort_t* __restrict__ xnfL, const ushort_t* __restrict__ xnfR,
    ushort_t* __restrict__ hnL, ushort_t* __restrict__ hnR,
    const ushort_t* __restrict__ zWp, const ushort_t* __restrict__ wisp,
    const float* __restrict__ zbias, const float* __restrict__ h0, int layer,
    uint_t* __restrict__ mb)
{
  __shared__ ushort_t A[2][16][136];  // [buf][row][hprev(0:64)|h(64:128)], +8 pad

  const int tid = threadIdx.x;
  const int g = blockIdx.x & 3;           // row group
  const int b = (blockIdx.x >> 2) & 15;
  const int d = blockIdx.x >> 6;
  const int ld = layer*2 + d;
  const ushort_t* xnf = d ? xnfR : xnfL;
  ushort_t* hp = d ? hnR : hnL;

  const int w = tid >> 6;             // wave = col group (16 cols per gate)
  const int lane = tid & 63;
  const int quad = lane >> 4;
  const int l16 = lane & 15;
  const int cg = w*16 + l16;

  // B fragments: all 4 gates of this wave's col group, wis + wss
  s8bf bss[4][4], bis[4][4];
#pragma unroll
  for (int kk = 0; kk < 4; kk++)
#pragma unroll
    for (int ct = 0; ct < 4; ct++){
      size_t fo = (size_t)(((kk*16 + (w + 4*ct))*64 + lane)*8);
      bss[kk][ct] = *(const s8bf*)(zWp  + (size_t)ld*32768 + fo);
      bis[kk][ct] = *(const s8bf*)(wisp + (size_t)ld*32768 + fo);
    }
  float zb[4];
#pragma unroll
  for (int ct = 0; ct < 4; ct++) zb[ct] = zbias[ld*256 + ct*64 + cg];

  float c_reg[4] = {0.f, 0.f, 0.f, 0.f};

  { // init both A buffers: h carry = h0 broadcast; hprev = h0 (global row 0 -> 0)
    int r2 = tid >> 4, q8 = tid & 15;
    const float* h0p = h0 + ld*64;
#pragma unroll
    for (int k = 0; k < 8; k++){
      int c = q8*8 + k;
      ushort_t hb = f2bf(h0p[c & 63]);
      ushort_t v;
      if (c < 64) v = (g == 0 && r2 == 0) ? (ushort_t)0 : hb;
      else        v = hb;
      A[0][r2][c] = v;
      A[1][r2][c] = v;
    }
  }

  // xf = xn(0) fragments (this group's 16-row tile); zxa(0); prefetch xn(1)
  const int stp8 = d ? -8192 : 8192;
  const ushort_t* xbase = xnf + ((size_t)b*127 + (d ? 126 : 0))*8192;
  uint4 xf[4];
#pragma unroll
  for (int kk = 0; kk < 4; kk++)
    xf[kk] = *(const uint4*)(xbase + (size_t)((kk*4 + g)*64 + lane)*8);

  f32x4 acc[4];
#pragma unroll
  for (int ct = 0; ct < 4; ct++) acc[ct] = splat4(zb[ct]);
#pragma unroll
  for (int kk = 0; kk < 4; kk++){
    s8bf a = *(const s8bf*)&xf[kk];
#pragma unroll
    for (int ct = 0; ct < 4; ct++)
      acc[ct] = __builtin_amdgcn_mfma_f32_16x16x32_bf16(a, bis[kk][ct], acc[ct], 0, 0, 0);
  }
  const ushort_t* pfp = xbase + stp8;   // next prefetch tile (t=1)
#pragma unroll
  for (int kk = 0; kk < 4; kk++)
    xf[kk] = *(const uint4*)(pfp + (size_t)((kk*4 + g)*64 + lane)*8);
  pfp += stp8;

  // running hn store pointer (lane base row = g*16 + quad*4, col cg)
  const int dj64 = d ? -64 : 64;
  ushort_t* hlane = hp + ((size_t)(b*64 + g*16 + quad*4)*N2 + (d ? 126 : 0))*64 + cg;

  // mailbox plumbing: link g = boundary below group g (rows 16g+15 / 16g+16)
  const int bd = b*2 + d;
  uint_t* mbOut = mb + ((size_t)(bd*3 + g)*127)*64;                 // g<3
  const uint_t* mbIn = mb + ((size_t)(bd*3 + (g > 0 ? g - 1 : 0))*127)*64;
  const uint_t stampBase = (uint_t)layer * 127u;
  const bool isProd = (g < 3);
  const bool isCons = (g > 0) && (w == 1);   // full wave: 1 col per lane

  __syncthreads();  // A init visible (full drain fine, once)

#pragma unroll 1
  for (int t = 0; t < 127; t++){
    const int pr = t & 1, pn = pr ^ 1;
    const uint_t stamp = stampBase + (uint_t)t + 1u;
    const bool doFetch = isCons && (t < 126);

    // early poll: issued now, first checked after zxa (MALL latency hidden)
    uint_t pv = 0;
    if (doFetch)
      pv = __hip_atomic_load(mbIn + (size_t)t*64 + lane,
                             __ATOMIC_RELAXED, __HIP_MEMORY_SCOPE_AGENT);

    // ---- phase A: acc += [hprev|h] @ wss ----
#pragma unroll
    for (int kk = 0; kk < 4; kk++){
      s8bf af = *(const s8bf*)&A[pr][l16][kk*32 + quad*8];
#pragma unroll
      for (int ct = 0; ct < 4; ct++)
        acc[ct] = __builtin_amdgcn_mfma_f32_16x16x32_bf16(af, bss[kk][ct], acc[ct], 0, 0, 0);
    }

    // ---- phase B: gates (VALU) + fire-and-forget boundary publish ----
#pragma unroll
    for (int r = 0; r < 4; r++){
      float fg = sigm(acc[0][r]);
      float ig = sigm(acc[1][r]);
      float og = sigm(acc[2][r]);
      float gg = tanhf_(acc[3][r]);
      float cn = fg*c_reg[r] + ig*gg;
      c_reg[r] = cn;
      float hn = og * tanhf_(cn);
      int rr = quad*4 + r;
      ushort_t hb = f2bf(hn);
      A[pn][rr][64 + cg] = hb;
      if (rr < 15) A[pn][rr + 1][cg] = hb;
      hlane[(size_t)r*8128] = hb;
      if (r == 3 && isProd && quad == 3 && t < 126)   // row 15 -> mailbox
        __hip_atomic_store(mbOut + (size_t)t*64 + cg,
                           (stamp << 16) | (uint_t)hb,
                           __ATOMIC_RELAXED, __HIP_MEMORY_SCOPE_AGENT);
    }
    hlane += dj64;

    // ---- phase B: zxa(t+1) = xn(t+1)@wis + zbias ----
    if (t < 126){
#pragma unroll
      for (int ct = 0; ct < 4; ct++) acc[ct] = splat4(zb[ct]);
#pragma unroll
      for (int kk = 0; kk < 4; kk++){
        s8bf a = *(const s8bf*)&xf[kk];
#pragma unroll
        for (int ct = 0; ct < 4; ct++)
          acc[ct] = __builtin_amdgcn_mfma_f32_16x16x32_bf16(a, bis[kk][ct], acc[ct], 0, 0, 0);
      }
      if (t < 125){
#pragma unroll
        for (int kk = 0; kk < 4; kk++)
          xf[kk] = *(const uint4*)(pfp + (size_t)((kk*4 + g)*64 + lane)*8);
        pfp += stp8;
      }
    }

    // ---- consumer: check stamped words; spin only while lead establishes
    if (doFetch){
      while (!__all((pv >> 16) == stamp))
        pv = __hip_atomic_load(mbIn + (size_t)t*64 + lane,
                               __ATOMIC_RELAXED, __HIP_MEMORY_SCOPE_AGENT);
      A[pn][0][lane] = (ushort_t)(pv & 0xffffu);   // neighbor h(t) -> hprev
    }

    // ---- raw barrier: LDS ordering only; global ops stay in flight ----
    __builtin_amdgcn_sched_barrier(0);
    asm volatile("s_waitcnt lgkmcnt(0)" ::: "memory");
    __builtin_amdgcn_s_barrier();
    __builtin_amdgcn_sched_barrier(0);
  }
}

// ---------------------------------------------------------------------------
// Head (512 threads): unskew + (128->32)->(32->32)->(32->256), fp32 vector.
// Stage-1/2: 16 row-groups x 4 rows.  Stage-3: jr loop split across 2 halves.
// ---------------------------------------------------------------------------
__global__ __launch_bounds__(512) void head_kernel(
    const ushort_t* __restrict__ xfin,
    const float* __restrict__ w1T, const float* __restrict__ b1,
    const float* __restrict__ w2T, const float* __restrict__ b2,
    const float* __restrict__ whT, const float* __restrict__ bh,
    float* __restrict__ out)
{
  __shared__ float xf[64][132];
  __shared__ float v1[64][36];
  __shared__ float v2[64][36];
  int tid = threadIdx.x;
  int b = blockIdx.x >> 6, i = blockIdx.x & 63;
  {
    int jj = tid >> 3, q = tid & 7;
    size_t base = ((size_t)(b*64 + i)*N2 + (i + jj))*128 + q*16;  // unskew
    const uint4* pL = (const uint4*)(xfin + base);
    float x[16];
    unpack8(pL[0], x); unpack8(pL[1], x+8);
#pragma unroll
    for (int k = 0; k < 16; k++) xf[jj][q*16 + k] = x[k];
  }
  __syncthreads();
  {
    int c1 = tid & 31, jg = tid >> 5;     // 16 groups x 4 rows
    float accv[4];
#pragma unroll
    for (int q = 0; q < 4; q++) accv[q] = b1[c1];
#pragma unroll 1
    for (int kc = 0; kc < 4; kc++){
      float wr[32];
      const float4* wp = (const float4*)(w1T + c1*128 + kc*32);
#pragma unroll
      for (int kk = 0; kk < 8; kk++) ((float4*)wr)[kk] = wp[kk];
#pragma unroll
      for (int jj2 = 0; jj2 < 4; jj2++){
        int jr = jg*4 + jj2;
        float a0=0.f,a1=0.f,a2=0.f,a3=0.f;
#pragma unroll
        for (int kk = 0; kk < 8; kk++){
          float4 xv = *(const float4*)&xf[jr][kc*32 + kk*4];
          a0 += xv.x*wr[kk*4]; a1 += xv.y*wr[kk*4+1]; a2 += xv.z*wr[kk*4+2]; a3 += xv.w*wr[kk*4+3];
        }
        accv[jj2] += (a0+a1)+(a2+a3);
      }
    }
#pragma unroll
    for (int jj2 = 0; jj2 < 4; jj2++) v1[jg*4 + jj2][c1] = accv[jj2];
  }
  __syncthreads();
  {
    int c2 = tid & 31, jg = tid >> 5;     // 16 groups x 4 rows
    float wr[32];
    const float4* wp = (const float4*)(w2T + c2*32);
#pragma unroll
    for (int kk = 0; kk < 8; kk++) ((float4*)wr)[kk] = wp[kk];
#pragma unroll
    for (int jj2 = 0; jj2 < 4; jj2++){
      int jr = jg*4 + jj2;
      float a0=0.f,a1=0.f,a2=0.f,a3=0.f;
#pragma unroll
      for (int kk = 0; kk < 8; kk++){
        float4 xv = *(const float4*)&v1[jr][kk*4];
        a0 += xv.x*wr[kk*4]; a1 += xv.y*wr[kk*4+1]; a2 += xv.z*wr[kk*4+2]; a3 += xv.w*wr[kk*4+3];
      }
      v2[jr][c2] = b2[c2] + (a0+a1)+(a2+a3);
    }
  }
  __syncthreads();
  {
    int o = tid & 255, jh = tid >> 8;     // two halves of the jr range
    float wr[32];
    const float4* wp = (const float4*)(whT + o*32);
#pragma unroll
    for (int kk = 0; kk < 8; kk++) ((float4*)wr)[kk] = wp[kk];
    float bo = bh[o];
#pragma unroll 1
    for (int jr2 = 0; jr2 < 32; jr2++){
      int jr = jh*32 + jr2;
      float a0=0.f,a1=0.f,a2=0.f,a3=0.f;
#pragma unroll
      for (int kk = 0; kk < 8; kk++){
        float4 xv = *(const float4*)&v2[jr][kk*4];
        a0 += xv.x*wr[kk*4]; a1 += xv.y*wr[kk*4+1]; a2 += xv.z*wr[kk*4+2]; a3 += xv.w*wr[kk*4+3];
      }
      out[(((size_t)b*64 + i)*64 + jr)*256 + o] = bo + (a0+a1)+(a2+a3);
    }
  }
}

// ---------------------------------------------------------------------------
extern "C" void kernel_launch(void* const* d_in, const int* in_sizes, int n_in,
                              void* d_out, int out_size, void* d_ws, size_t ws_size,
                              hipStream_t stream)
{
  const float* im   = (const float*)d_in[0];
  const float* ck   = (const float*)d_in[1];
  const float* cb   = (const float*)d_in[2];
  const float* ln_s = (const float*)d_in[3];
  const float* ln_b = (const float*)d_in[4];
  const float* w_is = (const float*)d_in[5];
  const float* b_is = (const float*)d_in[6];
  const float* w_ss = (const float*)d_in[7];
  const float* b_ss = (const float*)d_in[8];
  const float* w_oc = (const float*)d_in[9];
  const float* b_oc = (const float*)d_in[10];
  const float* h0   = (const float*)d_in[11];
  const float* w1   = (const float*)d_in[12];
  const float* b1   = (const float*)d_in[13];
  const float* w2   = (const float*)d_in[14];
  const float* b2   = (const float*)d_in[15];
  const float* wh   = (const float*)d_in[16];
  const float* bh   = (const float*)d_in[17];

  // Workspace layout: within Round-1's proven footprint (mailbox lives in
  // d_out, which is dead scratch until head_kernel writes it).
  ushort_t* Xbuf = (ushort_t*)d_ws;        // X0 -> X1 (aliased) -> xfin
  ushort_t* xnfL = Xbuf + ACT;             // xn fragment files (per layer, overwritten)
  ushort_t* xnfR = xnfL + ACT;
  ushort_t* hnL  = xnfR + ACT;
  ushort_t* hnR  = hnL + HNE;
  ushort_t* zWp  = hnR + HNE;              // wss frags  (131072 el)
  ushort_t* wisp = zWp + 131072;           // wis frags  (131072 el)
  ushort_t* wocp = wisp + 131072;          // woc frags  (32768 el)
  float* zbias = (float*)(wocp + 32768);
  float* w1T   = zbias + 1024;
  float* w2T   = w1T + 4096;
  float* whT   = w2T + 1024;
  uint_t* mb   = (uint_t*)d_out;           // stamped handoff mailbox (3.1 MB)

  prep_kernel<<<3006, 256, 0, stream>>>(im, cb, ck, w_is, w_ss, b_is, b_ss,
                                        w_oc, w1, w2, wh, Xbuf,
                                        zWp, wisp, wocp, zbias, w1T, w2T, whT, mb);
  stage0_kernel<<<2032, 512, 0, stream>>>(0, Xbuf, ln_s, ln_b, xnfL, xnfR);
  diag_kernel<<<128, 256, 0, stream>>>(xnfL, xnfR, hnL, hnR, zWp, wisp, zbias, h0, 0, mb);
  stage12_kernel<<<2032, 512, 0, stream>>>(1, 0, 1, Xbuf, hnL, hnR,
                                           wocp, b_oc, ln_s, ln_b, xnfL, xnfR);
  diag_kernel<<<128, 256, 0, stream>>>(xnfL, xnfR, hnL, hnR, zWp, wisp, zbias, h0, 1, mb);
  stage12_kernel<<<2032, 512, 0, stream>>>(2, 1, 0, Xbuf, hnL, hnR,
                                           wocp, b_oc, ln_s, ln_b, xnfL, xnfR);
  head_kernel<<<1024, 512, 0, stream>>>(Xbuf, w1T, b1, w2T, b2, whT, bh, (float*)d_out);
}

// Round 14
// 654.961 us; speedup vs baseline: 1.1488x; 1.0007x over previous
//
#include <hip/hip_runtime.h>

typedef unsigned short ushort_t;
typedef unsigned int uint_t;
typedef __attribute__((ext_vector_type(8))) short s8bf;   // 8 x bf16 MFMA fragment
typedef __attribute__((ext_vector_type(4))) float f32x4;  // MFMA accumulator

#define N2 127
#define ACT ((size_t)16*64*127*128)     // activation elements (bf16)
#define HNE ((size_t)16*64*127*64)      // hn elements (bf16)
#define MBW ((size_t)32*3*127*64)       // mailbox words (u32), lives in d_out

__device__ inline float bf_lo(uint_t v){ return __uint_as_float(v << 16); }
__device__ inline float bf_hi(uint_t v){ return __uint_as_float(v & 0xffff0000u); }
__device__ inline ushort_t f2bf(float f){
  uint_t u = __float_as_uint(f);
  uint_t r = ((u >> 16) & 1u) + 0x7fffu;  // RNE
  return (ushort_t)((u + r) >> 16);
}
// packed RNE f32x2 -> bf16x2 (same rounding as f2bf, 1 instr instead of ~10)
__device__ inline uint_t cvt_pk_bf16(float lo, float hi){
  uint_t r;
  asm("v_cvt_pk_bf16_f32 %0, %1, %2" : "=v"(r) : "v"(lo), "v"(hi));
  return r;
}
__device__ inline float bf2f(ushort_t h){ return __uint_as_float(((uint_t)h) << 16); }
__device__ inline float frcp(float x){ return __builtin_amdgcn_rcpf(x); }
__device__ inline float sigm(float x){ return frcp(1.f + __expf(-x)); }
__device__ inline float tanhf_(float x){
  // 1 - 2/(1+e^{2x}); saturates correctly for |x| large via inf/0, no clamp
  float e = __expf(2.f * x);
  return 1.f - 2.f * frcp(1.f + e);
}
__device__ inline void unpack8(uint4 u, float* x){
  x[0]=bf_lo(u.x); x[1]=bf_hi(u.x); x[2]=bf_lo(u.y); x[3]=bf_hi(u.y);
  x[4]=bf_lo(u.z); x[5]=bf_hi(u.z); x[6]=bf_lo(u.w); x[7]=bf_hi(u.w);
}
__device__ inline f32x4 zero4(){ f32x4 v; v[0]=0.f; v[1]=0.f; v[2]=0.f; v[3]=0.f; return v; }
__device__ inline f32x4 splat4(float s){ f32x4 v; v[0]=s; v[1]=s; v[2]=s; v[3]=s; return v; }

// 8 threads/row, 16 elems each
__device__ inline void rowstats16(const float* xr, float& mu, float& rstd){
  float s0=0.f, q0=0.f;
#pragma unroll
  for (int k = 0; k < 16; k++){ s0 += xr[k]; q0 += xr[k]*xr[k]; }
  s0 += __shfl_xor(s0, 1); q0 += __shfl_xor(q0, 1);
  s0 += __shfl_xor(s0, 2); q0 += __shfl_xor(q0, 2);
  s0 += __shfl_xor(s0, 4); q0 += __shfl_xor(q0, 4);
  mu = s0 * 0.0078125f;
  float var = q0 * 0.0078125f - mu*mu;
  rstd = rsqrtf(var + 1e-6f);
}

// ---------------------------------------------------------------------------
// prep_kernel = conv (blocks 0..1023) + pack (blocks 1024..3005), fused:
// conv reads ck directly (compile-time tap map) so it has no dependency on
// the pack half -- the two overlap inside one launch.
// ---------------------------------------------------------------------------
__global__ __launch_bounds__(256) void prep_kernel(
    const float* __restrict__ im, const float* __restrict__ cb,
    const float* __restrict__ ck,
    const float* __restrict__ w_is, const float* __restrict__ w_ss,
    const float* __restrict__ b_is, const float* __restrict__ b_ss,
    const float* __restrict__ w_oc, const float* __restrict__ w1,
    const float* __restrict__ w2, const float* __restrict__ wh,
    ushort_t* __restrict__ out,
    ushort_t* __restrict__ zWp, ushort_t* __restrict__ wisp,
    ushort_t* __restrict__ wocp,
    float* __restrict__ zbias, float* __restrict__ w1T,
    float* __restrict__ w2T, float* __restrict__ whT,
    uint_t* __restrict__ mb)
{
  __shared__ float ims[4][64];   // conv: rows i-3..i, zero-padded for ii<0
  const int tid = threadIdx.x;

  if (blockIdx.x < 1024){
    // ---------------- conv half ----------------
    const int b = blockIdx.x >> 6;
    const int i = blockIdx.x & 63;
    {
      int r = tid >> 6, c = tid & 63;
      int ii = i - 3 + r;
      ims[r][c] = (ii >= 0) ? im[(b*64 + ii)*64 + c] : 0.f;
    }
    const int ch = tid & 127;
    const int jh = tid >> 7;       // 0/1: even/odd j
    float kwreg[24];
#pragma unroll
    for (int tau = 0; tau < 24; tau++){
      int di = (tau < 21) ? (tau/7 - 3) : 0;
      int dj = (tau < 21) ? (tau%7 - 3) : (tau - 24);
      kwreg[tau] = ck[((di+3)*7 + (dj+3))*128 + ch];
    }
    const float cbv = cb[ch];
    __syncthreads();
    ushort_t* orow = out + ((size_t)(b*64 + i)*N2)*128 + ch;
#pragma unroll 1
    for (int jt = 0; jt < 64; jt++){
      int j = jt*2 + jh;
      if (j >= N2) break;
      int base = j - i;
      float acc = cbv;
#pragma unroll
      for (int tau = 0; tau < 24; tau++){
        int di = (tau < 21) ? (tau/7 - 3) : 0;
        int dj = (tau < 21) ? (tau%7 - 3) : (tau - 24);
        int jx = base + dj - di;
        int r = di + 3;
        if (jx >= 0 && jx < 64)
          acc += ims[r][jx] * kwreg[tau];
      }
      orow[(size_t)j*128] = f2bf(acc);
    }
    return;
  }

  // ---------------- pack half ----------------
  int idx = (blockIdx.x - 1024) * 256 + tid;
  if (idx < 131072){                        // zWp (wss): 4 ld x 32768
    int ld = idx >> 15; int r = idx & 32767;
    int e = r & 7, lane = (r >> 3) & 63, ctg = (r >> 9) & 15, kk = r >> 13;
    int k = kk*32 + ((lane >> 4) & 3)*8 + e;
    int n = ctg*16 + (lane & 15);
    float v;
    if (k < 64) v = w_ss[(((size_t)ld*2 + 0)*64 + k)*256 + n];
    else        v = w_ss[(((size_t)ld*2 + 1)*64 + (k-64))*256 + n];
    zWp[idx] = f2bf(v);
  } else if (idx < 262144){                 // wisp: 4 ld x 32768
    int r0 = idx - 131072;
    int ld = r0 >> 15; int r = r0 & 32767;
    int e = r & 7, lane = (r >> 3) & 63, ctg = (r >> 9) & 15, kk = r >> 13;
    int k = kk*32 + ((lane >> 4) & 3)*8 + e;
    int n = ctg*16 + (lane & 15);
    wisp[r0] = f2bf(w_is[((size_t)ld*128 + k)*256 + n]);
  } else if (idx < 294912){                 // wocp: 4 x 8192
    int r0 = idx - 262144;
    int ld = r0 >> 13; int r = r0 & 8191;
    int e = r & 7, lane = (r >> 3) & 63, ctg = (r >> 9) & 7, kk = (r >> 12) & 1;
    int k = kk*32 + ((lane >> 4) & 3)*8 + e;
    int n = ctg*16 + (lane & 15);
    wocp[r0] = f2bf(w_oc[((size_t)ld*64 + k)*128 + n]);
  } else if (idx < 295936){                 // fused z bias
    int r = idx - 294912;
    zbias[r] = b_is[r] + b_ss[r];
  } else if (idx < 300032){                 // w_out1^T (32,128)
    int r = idx - 295936;
    int c = r >> 7, k = r & 127;
    w1T[r] = w1[k*32 + c];
  } else if (idx < 301056){                 // w_out2^T (32,32)
    int r = idx - 300032;
    int c = r >> 5, k = r & 31;
    w2T[r] = w2[k*32 + c];
  } else if (idx < 309248){                 // w_head^T (256,32)
    int r = idx - 301056;
    int o = r >> 5, k = r & 31;
    whT[r] = wh[k*256 + o];
  } else if (idx >= 312320 && idx < (int)(312320 + MBW/4)){  // zero mailbox, 16B/thr
    ((uint4*)mb)[idx - 312320] = make_uint4(0u, 0u, 0u, 0u);
  }
}

// write_frags (512-thread): 8 wave-groups, 2 frag rows each
__device__ inline void write_frags512(const ushort_t* __restrict__ XN,
                                      ushort_t* __restrict__ dst, int tid){
  int lane = tid & 63, t8 = tid >> 6;
  int quad = (lane >> 4) & 3, l16 = lane & 15;
  int kk = t8 >> 1, rh = (t8 & 1)*2;
#pragma unroll
  for (int i = 0; i < 2; i++){
    int rt = rh + i;
    uint4 v = *(const uint4*)&XN[(size_t)(rt*16 + l16)*136 + kk*32 + quad*8];
    *(uint4*)(dst + (size_t)((kk*4 + rt)*64 + lane)*8) = v;
  }
}

// LN a 16-elem row-eighth into XN (512-thread layout)
__device__ inline void ln_to_XN16(ushort_t* __restrict__ XN, int row, int lq,
                                  const float* xr, float mu, float rstd,
                                  const float* __restrict__ ln_s,
                                  const float* __restrict__ ln_b, int ld){
  uint_t o[8];
#pragma unroll
  for (int k2 = 0; k2 < 8; k2++){
    int c = lq*16 + 2*k2;
    float a = (xr[2*k2]   - mu)*rstd*ln_s[ld*128 + c]     + ln_b[ld*128 + c];
    float b = (xr[2*k2+1] - mu)*rstd*ln_s[ld*128 + c + 1] + ln_b[ld*128 + c + 1];
    o[k2] = cvt_pk_bf16(a, b);
  }
  uint4* dst = (uint4*)&XN[(size_t)row*136 + lq*16];
  dst[0] = make_uint4(o[0], o[1], o[2], o[3]);
  dst[1] = make_uint4(o[4], o[5], o[6], o[7]);
}

// ---------------------------------------------------------------------------
// stage0 (512 threads): xn = LN(Xbuf; layer 0, both dirs) -> xnf frag files.
// ---------------------------------------------------------------------------
__global__ __launch_bounds__(512) void stage0_kernel(
    int lnlyr, const ushort_t* __restrict__ Xbuf,
    const float* __restrict__ ln_s, const float* __restrict__ ln_b,
    ushort_t* __restrict__ xnfL, ushort_t* __restrict__ xnfR)
{
  __shared__ __align__(16) ushort_t XN[64*136];    // 17408 B

  const int tid = threadIdx.x;
  const int bj = blockIdx.x;
  const int b = bj / 127, j = bj - b*127;
  const int row = tid >> 3, lq = tid & 7;

  float xr[16];
  {
    const uint4* p = (const uint4*)(Xbuf + ((size_t)(b*64 + row)*N2 + j)*128 + lq*16);
    unpack8(p[0], xr); unpack8(p[1], xr+8);
  }
  float mu, rstd;
  rowstats16(xr, mu, rstd);

  ln_to_XN16(XN, row, lq, xr, mu, rstd, ln_s, ln_b, lnlyr*2 + 0);
  __syncthreads();
  write_frags512(XN, xnfL + (size_t)bj*8192, tid);
  __syncthreads();
  ln_to_XN16(XN, row, lq, xr, mu, rstd, ln_s, ln_b, lnlyr*2 + 1);
  __syncthreads();
  write_frags512(XN, xnfR + (size_t)bj*8192, tid);
}

// ---------------------------------------------------------------------------
// stage12 (modes 1,2; 2032 blocks = (b,j), 512 threads / 8 waves).
// ---------------------------------------------------------------------------
__global__ __launch_bounds__(512, 1) void stage12_kernel(
    int mode, int woclyr, int lnlyr,
    ushort_t* __restrict__ Xbuf,
    const ushort_t* __restrict__ hnL, const ushort_t* __restrict__ hnR,
    const ushort_t* __restrict__ wocp, const float* __restrict__ b_oc,
    const float* __restrict__ ln_s, const float* __restrict__ ln_b,
    ushort_t* __restrict__ xnfL, ushort_t* __restrict__ xnfR)
{
  __shared__ __align__(16) float Xout[64*132];     // 33792 B
  __shared__ __align__(16) ushort_t XN[64*136];    // 17408 B
  __shared__ __align__(16) ushort_t XNh[64*72];    //  9216 B   (total 60416)

  const int tid = threadIdx.x;
  const int bj = blockIdx.x;
  const int b = bj / 127, j = bj - b*127;
  const int w8 = tid >> 6;                       // wave: 16-col group
  const int lane = tid & 63, quad = (lane >> 4) & 3, l16 = lane & 15;
  const int row = tid >> 3, lq = tid & 7;        // 8 threads/row, 16 cols each

  // this thread's X row-eighth (bf16 -> fp32 regs)
  float xr[16];
  {
    const uint4* p = (const uint4*)(Xbuf + ((size_t)(b*64 + row)*N2 + j)*128 + lq*16);
    unpack8(p[0], xr); unpack8(p[1], xr+8);
  }
  float mu, rstd;
  rowstats16(xr, mu, rstd);

  // ---- woc epilogues for both directions, combined with m-shift ----
#pragma unroll 1
  for (int s = 0; s < 2; s++){
    const int ld = woclyr*2 + s;
    ln_to_XN16(XN, row, lq, xr, mu, rstd, ln_s, ln_b, ld);   // residual xn
    {
      const ushort_t* hp = s ? hnR : hnL;
      const uint4* p = (const uint4*)(hp + ((size_t)(b*64 + row)*N2 + j)*64 + lq*8);
      *(uint4*)&XNh[(size_t)row*72 + lq*8] = p[0];
    }
    __syncthreads();
    s8bf bw[2];
#pragma unroll
    for (int kk = 0; kk < 2; kk++)
      bw[kk] = *(const s8bf*)(wocp + (size_t)ld*8192 + (size_t)(((kk*8 + w8)*64 + lane)*8));
    f32x4 a2[4];
#pragma unroll
    for (int rt = 0; rt < 4; rt++) a2[rt] = zero4();
#pragma unroll
    for (int kk = 0; kk < 2; kk++)
#pragma unroll
      for (int rt = 0; rt < 4; rt++){
        s8bf a = *(const s8bf*)&XNh[(size_t)(rt*16 + l16)*72 + kk*32 + quad*8];
        a2[rt] = __builtin_amdgcn_mfma_f32_16x16x32_bf16(a, bw[kk], a2[rt], 0, 0, 0);
      }
    const float bv = b_oc[ld*128 + w8*16 + l16];
    const int col = w8*16 + l16;
#pragma unroll
    for (int rt = 0; rt < 4; rt++)
#pragma unroll
      for (int r = 0; r < 4; r++){
        int rr = rt*16 + quad*4 + r;
        float v = a2[rt][r] + bv + bf2f(XN[(size_t)rr*136 + col]);
        if (s == 0) Xout[(size_t)rr*132 + col] = v;
        else if (rr < 63) Xout[(size_t)(rr + 1)*132 + col] += v;  // m-shift; row 0 = left only
      }
    __syncthreads();
  }

  // ---- write combined X back to Xbuf (own j-slice; reads all done) ----
  float xo[16];
#pragma unroll
  for (int k = 0; k < 16; k++) xo[k] = Xout[(size_t)row*132 + lq*16 + k];
  {
    uint_t o[8];
#pragma unroll
    for (int k = 0; k < 8; k++) o[k] = cvt_pk_bf16(xo[2*k], xo[2*k + 1]);
    uint4* dst = (uint4*)(Xbuf + ((size_t)(b*64 + row)*N2 + j)*128 + lq*16);
    dst[0] = make_uint4(o[0], o[1], o[2], o[3]);
    dst[1] = make_uint4(o[4], o[5], o[6], o[7]);
  }
  if (mode == 2) return;

  // ---- LN for the next layer -> fragment files ----
  float mu2, rstd2;
  rowstats16(xo, mu2, rstd2);
  ln_to_XN16(XN, row, lq, xo, mu2, rstd2, ln_s, ln_b, lnlyr*2 + 0);
  __syncthreads();
  write_frags512(XN, xnfL + (size_t)bj*8192, tid);
  __syncthreads();
  ln_to_XN16(XN, row, lq, xo, mu2, rstd2, ln_s, ln_b, lnlyr*2 + 1);
  __syncthreads();
  write_frags512(XN, xnfR + (size_t)bj*8192, tid);
}

// ---------------------------------------------------------------------------
// Diagonal LSTM recurrence, row-split 4 ways: 128 blocks = (d, b, g) with
// row group g owning rows 16g..16g+15.  256 threads / 4 waves; wave w owns
// h-col group w (16 cols x 4 gates).  Cross-group coupling is only the
// one-row hprev shift, handled by a stamped mailbox in d_out scratch:
//   word[col] = (stamp16 << 16) | h_bf16,  stamp = layer*127 + t + 1.
// Producer lanes (quad==3, r==3 hold row 15) fire agent-scope stores from
// registers during the gate phase -- no vmcnt drain, no ordering fence
// (stamp and data share the word, u32 stores are atomic).  Consumer polls
// its 64 words (load issued at loop top, checked after zxa -> MALL latency
// hidden).  Producers never wait on consumers -> no deadlock.
// LDS A double-buffered -> ONE barrier per step via __syncthreads()
// (PROVEN: both raw-barrier variants regressed; this is the 161.7us form).
// ---------------------------------------------------------------------------
__global__ __launch_bounds__(256, 1) void diag_kernel(
    const ushort_t* __restrict__ xnfL, const ushort_t* __restrict__ xnfR,
    ushort_t* __restrict__ hnL, ushort_t* __restrict__ hnR,
    const ushort_t* __restrict__ zWp, const ushort_t* __restrict__ wisp,
    const float* __restrict__ zbias, const float* __restrict__ h0, int layer,
    uint_t* __restrict__ mb)
{
  __shared__ ushort_t A[2][16][136];  // [buf][row][hprev(0:64)|h(64:128)], +8 pad

  const int tid = threadIdx.x;
  const int g = blockIdx.x & 3;           // row group
  const int b = (blockIdx.x >> 2) & 15;
  const int d = blockIdx.x >> 6;
  const int ld = layer*2 + d;
  const ushort_t* xnf = d ? xnfR : xnfL;
  ushort_t* hp = d ? hnR : hnL;

  const int w = tid >> 6;             // wave = col group (16 cols per gate)
  const int lane = tid & 63;
  const int quad = lane >> 4;
  const int l16 = lane & 15;
  const int cg = w*16 + l16;

  // B fragments: all 4 gates of this wave's col group, wis + wss
  s8bf bss[4][4], bis[4][4];
#pragma unroll
  for (int kk = 0; kk < 4; kk++)
#pragma unroll
    for (int ct = 0; ct < 4; ct++){
      size_t fo = (size_t)(((kk*16 + (w + 4*ct))*64 + lane)*8);
      bss[kk][ct] = *(const s8bf*)(zWp  + (size_t)ld*32768 + fo);
      bis[kk][ct] = *(const s8bf*)(wisp + (size_t)ld*32768 + fo);
    }
  float zb[4];
#pragma unroll
  for (int ct = 0; ct < 4; ct++) zb[ct] = zbias[ld*256 + ct*64 + cg];

  float c_reg[4] = {0.f, 0.f, 0.f, 0.f};

  { // init both A buffers: h carry = h0 broadcast; hprev = h0 (global row 0 -> 0)
    int r2 = tid >> 4, q8 = tid & 15;
    const float* h0p = h0 + ld*64;
#pragma unroll
    for (int k = 0; k < 8; k++){
      int c = q8*8 + k;
      ushort_t hb = f2bf(h0p[c & 63]);
      ushort_t v;
      if (c < 64) v = (g == 0 && r2 == 0) ? (ushort_t)0 : hb;
      else        v = hb;
      A[0][r2][c] = v;
      A[1][r2][c] = v;
    }
  }

  // xf = xn(0) fragments (this group's 16-row tile); zxa(0); prefetch xn(1)
  const int stp8 = d ? -8192 : 8192;
  const ushort_t* xbase = xnf + ((size_t)b*127 + (d ? 126 : 0))*8192;
  uint4 xf[4];
#pragma unroll
  for (int kk = 0; kk < 4; kk++)
    xf[kk] = *(const uint4*)(xbase + (size_t)((kk*4 + g)*64 + lane)*8);

  f32x4 acc[4];
#pragma unroll
  for (int ct = 0; ct < 4; ct++) acc[ct] = splat4(zb[ct]);
#pragma unroll
  for (int kk = 0; kk < 4; kk++){
    s8bf a = *(const s8bf*)&xf[kk];
#pragma unroll
    for (int ct = 0; ct < 4; ct++)
      acc[ct] = __builtin_amdgcn_mfma_f32_16x16x32_bf16(a, bis[kk][ct], acc[ct], 0, 0, 0);
  }
  const ushort_t* pfp = xbase + stp8;   // next prefetch tile (t=1)
#pragma unroll
  for (int kk = 0; kk < 4; kk++)
    xf[kk] = *(const uint4*)(pfp + (size_t)((kk*4 + g)*64 + lane)*8);
  pfp += stp8;

  // running hn store pointer (lane base row = g*16 + quad*4, col cg)
  const int dj64 = d ? -64 : 64;
  ushort_t* hlane = hp + ((size_t)(b*64 + g*16 + quad*4)*N2 + (d ? 126 : 0))*64 + cg;

  // mailbox plumbing: link g = boundary below group g (rows 16g+15 / 16g+16)
  const int bd = b*2 + d;
  uint_t* mbOut = mb + ((size_t)(bd*3 + g)*127)*64;                 // g<3
  const uint_t* mbIn = mb + ((size_t)(bd*3 + (g > 0 ? g - 1 : 0))*127)*64;
  const uint_t stampBase = (uint_t)layer * 127u;
  const bool isProd = (g < 3);
  const bool isCons = (g > 0) && (w == 1);   // full wave: 1 col per lane

  __syncthreads();  // A init visible

#pragma unroll 1
  for (int t = 0; t < 127; t++){
    const int pr = t & 1, pn = pr ^ 1;
    const uint_t stamp = stampBase + (uint_t)t + 1u;
    const bool doFetch = isCons && (t < 126);

    // early poll: issued now, first checked after zxa (MALL latency hidden)
    uint_t pv = 0;
    if (doFetch)
      pv = __hip_atomic_load(mbIn + (size_t)t*64 + lane,
                             __ATOMIC_RELAXED, __HIP_MEMORY_SCOPE_AGENT);

    // ---- phase A: acc += [hprev|h] @ wss ----
#pragma unroll
    for (int kk = 0; kk < 4; kk++){
      s8bf af = *(const s8bf*)&A[pr][l16][kk*32 + quad*8];
#pragma unroll
      for (int ct = 0; ct < 4; ct++)
        acc[ct] = __builtin_amdgcn_mfma_f32_16x16x32_bf16(af, bss[kk][ct], acc[ct], 0, 0, 0);
    }

    // ---- phase B: gates (VALU) + fire-and-forget boundary publish ----
#pragma unroll
    for (int r = 0; r < 4; r++){
      float fg = sigm(acc[0][r]);
      float ig = sigm(acc[1][r]);
      float og = sigm(acc[2][r]);
      float gg = tanhf_(acc[3][r]);
      float cn = fg*c_reg[r] + ig*gg;
      c_reg[r] = cn;
      float hn = og * tanhf_(cn);
      int rr = quad*4 + r;
      ushort_t hb = f2bf(hn);
      A[pn][rr][64 + cg] = hb;
      if (rr < 15) A[pn][rr + 1][cg] = hb;
      hlane[(size_t)r*8128] = hb;
      if (r == 3 && isProd && quad == 3 && t < 126)   // row 15 -> mailbox
        __hip_atomic_store(mbOut + (size_t)t*64 + cg,
                           (stamp << 16) | (uint_t)hb,
                           __ATOMIC_RELAXED, __HIP_MEMORY_SCOPE_AGENT);
    }
    hlane += dj64;

    // ---- phase B: zxa(t+1) = xn(t+1)@wis + zbias ----
    if (t < 126){
#pragma unroll
      for (int ct = 0; ct < 4; ct++) acc[ct] = splat4(zb[ct]);
#pragma unroll
      for (int kk = 0; kk < 4; kk++){
        s8bf a = *(const s8bf*)&xf[kk];
#pragma unroll
        for (int ct = 0; ct < 4; ct++)
          acc[ct] = __builtin_amdgcn_mfma_f32_16x16x32_bf16(a, bis[kk][ct], acc[ct], 0, 0, 0);
      }
      if (t < 125){
#pragma unroll
        for (int kk = 0; kk < 4; kk++)
          xf[kk] = *(const uint4*)(pfp + (size_t)((kk*4 + g)*64 + lane)*8);
        pfp += stp8;
      }
    }

    // ---- consumer: check stamped words; spin only while lead establishes
    if (doFetch){
      while (!__all((pv >> 16) == stamp))
        pv = __hip_atomic_load(mbIn + (size_t)t*64 + lane,
                               __ATOMIC_RELAXED, __HIP_MEMORY_SCOPE_AGENT);
      A[pn][0][lane] = (ushort_t)(pv & 0xffffu);   // neighbor h(t) -> hprev
    }

    __syncthreads(); // new h/hprev (buffer pn) visible for next phase A
  }
}

// ---------------------------------------------------------------------------
// Head (512 threads): unskew + (128->32)->(32->32)->(32->256), fp32 vector.
// ---------------------------------------------------------------------------
__global__ __launch_bounds__(512) void head_kernel(
    const ushort_t* __restrict__ xfin,
    const float* __restrict__ w1T, const float* __restrict__ b1,
    const float* __restrict__ w2T, const float* __restrict__ b2,
    const float* __restrict__ whT, const float* __restrict__ bh,
    float* __restrict__ out)
{
  __shared__ float xf[64][132];
  __shared__ float v1[64][36];
  __shared__ float v2[64][36];
  int tid = threadIdx.x;
  int b = blockIdx.x >> 6, i = blockIdx.x & 63;
  {
    int jj = tid >> 3, q = tid & 7;
    size_t base = ((size_t)(b*64 + i)*N2 + (i + jj))*128 + q*16;  // unskew
    const uint4* pL = (const uint4*)(xfin + base);
    float x[16];
    unpack8(pL[0], x); unpack8(pL[1], x+8);
#pragma unroll
    for (int k = 0; k < 16; k++) xf[jj][q*16 + k] = x[k];
  }
  __syncthreads();
  {
    int c1 = tid & 31, jg = tid >> 5;     // 16 groups x 4 rows
    float accv[4];
#pragma unroll
    for (int q = 0; q < 4; q++) accv[q] = b1[c1];
#pragma unroll 1
    for (int kc = 0; kc < 4; kc++){
      float wr[32];
      const float4* wp = (const float4*)(w1T + c1*128 + kc*32);
#pragma unroll
      for (int kk = 0; kk < 8; kk++) ((float4*)wr)[kk] = wp[kk];
#pragma unroll
      for (int jj2 = 0; jj2 < 4; jj2++){
        int jr = jg*4 + jj2;
        float a0=0.f,a1=0.f,a2=0.f,a3=0.f;
#pragma unroll
        for (int kk = 0; kk < 8; kk++){
          float4 xv = *(const float4*)&xf[jr][kc*32 + kk*4];
          a0 += xv.x*wr[kk*4]; a1 += xv.y*wr[kk*4+1]; a2 += xv.z*wr[kk*4+2]; a3 += xv.w*wr[kk*4+3];
        }
        accv[jj2] += (a0+a1)+(a2+a3);
      }
    }
#pragma unroll
    for (int jj2 = 0; jj2 < 4; jj2++) v1[jg*4 + jj2][c1] = accv[jj2];
  }
  __syncthreads();
  {
    int c2 = tid & 31, jg = tid >> 5;     // 16 groups x 4 rows
    float wr[32];
    const float4* wp = (const float4*)(w2T + c2*32);
#pragma unroll
    for (int kk = 0; kk < 8; kk++) ((float4*)wr)[kk] = wp[kk];
#pragma unroll
    for (int jj2 = 0; jj2 < 4; jj2++){
      int jr = jg*4 + jj2;
      float a0=0.f,a1=0.f,a2=0.f,a3=0.f;
#pragma unroll
      for (int kk = 0; kk < 8; kk++){
        float4 xv = *(const float4*)&v1[jr][kk*4];
        a0 += xv.x*wr[kk*4]; a1 += xv.y*wr[kk*4+1]; a2 += xv.z*wr[kk*4+2]; a3 += xv.w*wr[kk*4+3];
      }
      v2[jr][c2] = b2[c2] + (a0+a1)+(a2+a3);
    }
  }
  __syncthreads();
  {
    int o = tid & 255, jh = tid >> 8;     // two halves of the jr range
    float wr[32];
    const float4* wp = (const float4*)(whT + o*32);
#pragma unroll
    for (int kk = 0; kk < 8; kk++) ((float4*)wr)[kk] = wp[kk];
    float bo = bh[o];
#pragma unroll 1
    for (int jr2 = 0; jr2 < 32; jr2++){
      int jr = jh*32 + jr2;
      float a0=0.f,a1=0.f,a2=0.f,a3=0.f;
#pragma unroll
      for (int kk = 0; kk < 8; kk++){
        float4 xv = *(const float4*)&v2[jr][kk*4];
        a0 += xv.x*wr[kk*4]; a1 += xv.y*wr[kk*4+1]; a2 += xv.z*wr[kk*4+2]; a3 += xv.w*wr[kk*4+3];
      }
      out[(((size_t)b*64 + i)*64 + jr)*256 + o] = bo + (a0+a1)+(a2+a3);
    }
  }
}

// ---------------------------------------------------------------------------
extern "C" void kernel_launch(void* const* d_in, const int* in_sizes, int n_in,
                              void* d_out, int out_size, void* d_ws, size_t ws_size,
                              hipStream_t stream)
{
  const float* im   = (const float*)d_in[0];
  const float* ck   = (const float*)d_in[1];
  const float* cb   = (const float*)d_in[2];
  const float* ln_s = (const float*)d_in[3];
  const float* ln_b = (const float*)d_in[4];
  const float* w_is = (const float*)d_in[5];
  const float* b_is = (const float*)d_in[6];
  const float* w_ss = (const float*)d_in[7];
  const float* b_ss = (const float*)d_in[8];
  const float* w_oc = (const float*)d_in[9];
  const float* b_oc = (const float*)d_in[10];
  const float* h0   = (const float*)d_in[11];
  const float* w1   = (const float*)d_in[12];
  const float* b1   = (const float*)d_in[13];
  const float* w2   = (const float*)d_in[14];
  const float* b2   = (const float*)d_in[15];
  const float* wh   = (const float*)d_in[16];
  const float* bh   = (const float*)d_in[17];

  // Workspace layout: within Round-1's proven footprint (mailbox lives in
  // d_out, which is dead scratch until head_kernel writes it).
  ushort_t* Xbuf = (ushort_t*)d_ws;        // X0 -> X1 (aliased) -> xfin
  ushort_t* xnfL = Xbuf + ACT;             // xn fragment files (per layer, overwritten)
  ushort_t* xnfR = xnfL + ACT;
  ushort_t* hnL  = xnfR + ACT;
  ushort_t* hnR  = hnL + HNE;
  ushort_t* zWp  = hnR + HNE;              // wss frags  (131072 el)
  ushort_t* wisp = zWp + 131072;           // wis frags  (131072 el)
  ushort_t* wocp = wisp + 131072;          // woc frags  (32768 el)
  float* zbias = (float*)(wocp + 32768);
  float* w1T   = zbias + 1024;
  float* w2T   = w1T + 4096;
  float* whT   = w2T + 1024;
  uint_t* mb   = (uint_t*)d_out;           // stamped handoff mailbox (3.1 MB)

  prep_kernel<<<3006, 256, 0, stream>>>(im, cb, ck, w_is, w_ss, b_is, b_ss,
                                        w_oc, w1, w2, wh, Xbuf,
                                        zWp, wisp, wocp, zbias, w1T, w2T, whT, mb);
  stage0_kernel<<<2032, 512, 0, stream>>>(0, Xbuf, ln_s, ln_b, xnfL, xnfR);
  diag_kernel<<<128, 256, 0, stream>>>(xnfL, xnfR, hnL, hnR, zWp, wisp, zbias, h0, 0, mb);
  stage12_kernel<<<2032, 512, 0, stream>>>(1, 0, 1, Xbuf, hnL, hnR,
                                           wocp, b_oc, ln_s, ln_b, xnfL, xnfR);
  diag_kernel<<<128, 256, 0, stream>>>(xnfL, xnfR, hnL, hnR, zWp, wisp, zbias, h0, 1, mb);
  stage12_kernel<<<2032, 512, 0, stream>>>(2, 1, 0, Xbuf, hnL, hnR,
                                           wocp, b_oc, ln_s, ln_b, xnfL, xnfR);
  head_kernel<<<1024, 512, 0, stream>>>(Xbuf, w1T, b1, w2T, b2, whT, bh, (float*)d_out);
}